// Round 12
// baseline (1455.559 us; speedup 1.0000x reference)
//
#include <hip/hip_runtime.h>

// ---------------------------------------------------------------------------
// AttentionLayer: B=16 S=12 N=400 D=512 H=8 HD=64
// outputs (flat, fp32): out[16,12,400,512] | scores_hb[128,12,400,400]
//                       | v_hb[128,12,400,64]
// NOTE (r3, r9): __builtin_nontemporal_store on these fragment epilogues is a
// ~2x write-cost regression — per-instruction segments are 64B, not full
// 128B lines; L2 write-merge is load-bearing. Do not reintroduce NT.
// NOTE (r8): HW v_cvt_pk_bf16_f32 is not RNE — absmax 7.9e-2 fail. Use f2bf.
// NOTE (r11): GEMM K-loops are 2-phase double-buffered (one barrier/k-step).
// NOTE (r12): DIAGNOSTIC ROUND — proj_k and outgemm_k are launched TWICE
// (both idempotent; attn_k cannot be doubled: ctx aliases wq_).
//   proj+outgemm = dur(r12) − dur(r11);  attn+cvtw = dur(r11) − that.
// Revert to single launches next round.
// ---------------------------------------------------------------------------

typedef float fvec4 __attribute__((ext_vector_type(4)));
typedef float f32x4 __attribute__((ext_vector_type(4)));
typedef unsigned short usvec4 __attribute__((ext_vector_type(4)));
typedef unsigned short usvec8 __attribute__((ext_vector_type(8)));
typedef short v8s __attribute__((ext_vector_type(8)));

#define DEV __device__ __forceinline__

DEV unsigned short f2bf(float f) {
  unsigned int u = __builtin_bit_cast(unsigned int, f);
  u += 0x7FFFu + ((u >> 16) & 1u);  // RNE
  return (unsigned short)(u >> 16);
}

DEV f32x4 mfma16(v8s a, v8s b, f32x4 c) {
  return __builtin_amdgcn_mfma_f32_16x16x32_bf16(a, b, c, 0, 0, 0);
}

DEV void gload16(const void* g, void* l) {
  __builtin_amdgcn_global_load_lds(
      (const __attribute__((address_space(1))) unsigned int*)g,
      (__attribute__((address_space(3))) unsigned int*)l, 16, 0, 0);
}

// all 4 weight matrices (512x512 each) in one launch; blockIdx.y selects
__global__ __launch_bounds__(256) void cvtw_k(const float* __restrict__ w0,
                                              const float* __restrict__ w1,
                                              const float* __restrict__ w2,
                                              const float* __restrict__ w3,
                                              unsigned short* __restrict__ o) {
  const float* w = (blockIdx.y == 0) ? w0 : (blockIdx.y == 1) ? w1
                 : (blockIdx.y == 2) ? w2 : w3;
  unsigned short* op = o + (long)blockIdx.y * 262144;
  long i = ((long)blockIdx.x * 256 + threadIdx.x) * 8;  // grid.x=128 -> exact
  fvec4 a = *reinterpret_cast<const fvec4*>(w + i);
  fvec4 b = *reinterpret_cast<const fvec4*>(w + i + 4);
  usvec8 r;
  r[0] = f2bf(a[0]); r[1] = f2bf(a[1]); r[2] = f2bf(a[2]); r[3] = f2bf(a[3]);
  r[4] = f2bf(b[0]); r[5] = f2bf(b[1]); r[6] = f2bf(b[2]); r[7] = f2bf(b[3]);
  *reinterpret_cast<usvec8*>(op + i) = r;
}

// ---------------------------------------------------------------------------
// Merged projection GEMM (q,k,v in ONE launch; grid 7200 = 8*900 XCD-chunked).
// 2-phase dbuf; A fp32 reg-staged cvt; B gload16.
// ---------------------------------------------------------------------------
__global__ __launch_bounds__(256) void proj_k(
    const float* __restrict__ qin, const float* __restrict__ kin,
    const float* __restrict__ vin, const unsigned short* __restrict__ wW,
    const float* __restrict__ bqp, const float* __restrict__ bkp,
    const float* __restrict__ bvp, unsigned short* __restrict__ wq_,
    unsigned short* __restrict__ wk_, float* __restrict__ vhb,
    unsigned short* __restrict__ wvt) {
  // shorts: A bufs [0,4096),[4096,8192); B bufs [8192,12288),[12288,16384)
  // C-tile epilogue overlays [0, 17408)
  __shared__ unsigned short sMem[128 * 136];
  const int t = threadIdx.x;
  const int lane = t & 63, wid = t >> 6;
  const int wm = wid >> 1, wn = wid & 1;
  const int lr = lane & 15, lg = lane >> 4;
  const int bid = blockIdx.x;
  const int orig = (bid & 7) * 900 + (bid >> 3);
  const int which = orig >= 4800 ? 2 : (orig >= 2400 ? 1 : 0);
  const int inner = orig - which * 2400;
  const long m0 = (long)(inner >> 2) * 128;
  const int n0 = (inner & 3) * 128;

  const float* A = which == 0 ? qin : which == 1 ? kin : vin;
  const unsigned short* W = wW + (long)which * 262144;
  const float* bias = which == 0 ? bqp : which == 1 ? bkp : bvp;

  const int srow = wid * 16 + (lane >> 2);
  const int scol = (lane & 3) * 8;
  const unsigned short* bS0 = W + (long)(n0 + srow) * 512 + scol;
  const unsigned short* bS1 = bS0 + 64 * 512;
  const int bOff0 = wid * 512;
  const int bOff1 = (wid + 4) * 512;

  const int arow = t >> 3;       // 0..31
  const int acol = (t & 7) * 4;  // f32 col within k-tile
  const float* aP32 = A + (m0 + arow) * 512 + acol;
  const int aOff = arow * 32 + acol;

  f32x4 acc[4][4] = {};
  fvec4 aReg[4];
#pragma unroll
  for (int i = 0; i < 4; i++)
    aReg[i] = *reinterpret_cast<const fvec4*>(aP32 + (long)i * 16384);

  {  // prologue: stage tile 0 into buf0, prefetch A regs for tile 1
    unsigned short* sA0 = sMem;
    unsigned short* sB0 = sMem + 8192;
    gload16(bS0, sB0 + bOff0);
    gload16(bS1, sB0 + bOff1);
#pragma unroll
    for (int i = 0; i < 4; i++) {
      usvec4 pk;
      pk[0] = f2bf(aReg[i][0]); pk[1] = f2bf(aReg[i][1]);
      pk[2] = f2bf(aReg[i][2]); pk[3] = f2bf(aReg[i][3]);
      *reinterpret_cast<usvec4*>(sA0 + aOff + i * 1024) = pk;
    }
#pragma unroll
    for (int i = 0; i < 4; i++)
      aReg[i] = *reinterpret_cast<const fvec4*>(aP32 + (long)i * 16384 + 32);
  }
  __syncthreads();

  for (int k0 = 0; k0 < 512; k0 += 32) {
    const int c = (k0 >> 5) & 1;
    unsigned short* sAc = sMem + c * 4096;
    unsigned short* sBc = sMem + 8192 + c * 4096;
    if (k0 < 480) {  // stage tile k0+32 into buf^1
      unsigned short* sAn = sMem + (c ^ 1) * 4096;
      unsigned short* sBn = sMem + 8192 + (c ^ 1) * 4096;
      gload16(bS0 + k0 + 32, sBn + bOff0);
      gload16(bS1 + k0 + 32, sBn + bOff1);
#pragma unroll
      for (int i = 0; i < 4; i++) {
        usvec4 pk;
        pk[0] = f2bf(aReg[i][0]); pk[1] = f2bf(aReg[i][1]);
        pk[2] = f2bf(aReg[i][2]); pk[3] = f2bf(aReg[i][3]);
        *reinterpret_cast<usvec4*>(sAn + aOff + i * 1024) = pk;
      }
      if (k0 < 448) {
#pragma unroll
        for (int i = 0; i < 4; i++)
          aReg[i] = *reinterpret_cast<const fvec4*>(aP32 + (long)i * 16384 +
                                                    k0 + 64);
      }
    }

    v8s af[4], bf[4];
#pragma unroll
    for (int i = 0; i < 4; i++)
      af[i] = *reinterpret_cast<const v8s*>(&sAc[(wm * 64 + i * 16 + lr) * 32 + lg * 8]);
#pragma unroll
    for (int j = 0; j < 4; j++)
      bf[j] = *reinterpret_cast<const v8s*>(&sBc[(wn * 64 + j * 16 + lr) * 32 + lg * 8]);
#pragma unroll
    for (int i = 0; i < 4; i++)
#pragma unroll
      for (int j = 0; j < 4; j++) acc[i][j] = mfma16(af[i], bf[j], acc[i][j]);
    __syncthreads();
  }

  if (which <= 1) {
    unsigned short* o_h = which == 0 ? wq_ : wk_;
#pragma unroll
    for (int i = 0; i < 4; i++) {
#pragma unroll
      for (int j = 0; j < 4; j++) {
        const int col = wn * 64 + j * 16 + lr;
        const float bv_ = bias[n0 + col];
#pragma unroll
        for (int r = 0; r < 4; r++) {
          const int row = wm * 64 + i * 16 + lg * 4 + r;
          sMem[row * 136 + col] = f2bf(acc[i][j][r] + bv_);
        }
      }
    }
    __syncthreads();
#pragma unroll
    for (int pass = 0; pass < 2; pass++) {
      const int row = (t >> 2) + pass * 64;
      const int c0 = (t & 3) * 8;
      const unsigned short* src = &sMem[row * 136 + c0];
      unsigned short* dst = &o_h[(m0 + row) * 512 + n0 + c0];
#pragma unroll
      for (int k = 0; k < 4; k++)
        *reinterpret_cast<usvec8*>(dst + k * 32) =
            *reinterpret_cast<const usvec8*>(src + k * 32);
    }
  } else {
#pragma unroll
    for (int i = 0; i < 4; i++) {
#pragma unroll
      for (int j = 0; j < 4; j++) {
        const int gn = n0 + wn * 64 + j * 16 + lr;
        const float bv_ = bias[gn];
        const long gm0 = m0 + wm * 64 + i * 16 + lg * 4;
        const int bs_lin = (int)(gm0 / 400);
        const int node0 = (int)(gm0 - (long)bs_lin * 400);
        const int h = gn >> 6, hd = gn & 63;
        float* vp = vhb + ((((long)(h * 192 + bs_lin) * 400 + node0) << 6) + hd);
        const float v0 = acc[i][j][0] + bv_, v1 = acc[i][j][1] + bv_;
        const float v2 = acc[i][j][2] + bv_, v3 = acc[i][j][3] + bv_;
        vp[0] = v0;
        vp[64] = v1;
        vp[128] = v2;
        vp[192] = v3;
        usvec4 pk;
        pk[0] = f2bf(v0); pk[1] = f2bf(v1); pk[2] = f2bf(v2); pk[3] = f2bf(v3);
        *reinterpret_cast<usvec4*>(
            wvt + (((long)(bs_lin * 8 + h) * 64 + hd) * 400 + node0)) = pk;
      }
    }
  }
}

// ---------------------------------------------------------------------------
// Output GEMM: 2-phase dbuf, gload16 A and B.
// ---------------------------------------------------------------------------
__global__ __launch_bounds__(256) void outgemm_k(
    const unsigned short* __restrict__ A, const unsigned short* __restrict__ W,
    const float* __restrict__ bias, float* __restrict__ o_f) {
  __shared__ unsigned short sMem[16384];
  const int t = threadIdx.x;
  const int lane = t & 63, wid = t >> 6;
  const int wm = wid >> 1, wn = wid & 1;
  const int lr = lane & 15, lg = lane >> 4;
  const int bid = blockIdx.x;
  const int orig = (bid & 7) * 300 + (bid >> 3);
  const long m0 = (long)(orig >> 2) * 128;
  const int n0 = (orig & 3) * 128;

  const int srow = wid * 16 + (lane >> 2);
  const int scol = (lane & 3) * 8;
  const unsigned short* aS0 = A + (m0 + srow) * 512 + scol;
  const unsigned short* aS1 = aS0 + 64 * 512;
  const unsigned short* bS0 = W + (long)(n0 + srow) * 512 + scol;
  const unsigned short* bS1 = bS0 + 64 * 512;
  const int bOff0 = wid * 512;
  const int bOff1 = (wid + 4) * 512;

  f32x4 acc[4][4] = {};

  {
    gload16(aS0, sMem + bOff0);
    gload16(aS1, sMem + bOff1);
    gload16(bS0, sMem + 8192 + bOff0);
    gload16(bS1, sMem + 8192 + bOff1);
  }
  __syncthreads();

  for (int k0 = 0; k0 < 512; k0 += 32) {
    const int c = (k0 >> 5) & 1;
    unsigned short* sAc = sMem + c * 4096;
    unsigned short* sBc = sMem + 8192 + c * 4096;
    if (k0 < 480) {
      unsigned short* sAn = sMem + (c ^ 1) * 4096;
      unsigned short* sBn = sMem + 8192 + (c ^ 1) * 4096;
      gload16(aS0 + k0 + 32, sAn + bOff0);
      gload16(aS1 + k0 + 32, sAn + bOff1);
      gload16(bS0 + k0 + 32, sBn + bOff0);
      gload16(bS1 + k0 + 32, sBn + bOff1);
    }

    v8s af[4], bf[4];
#pragma unroll
    for (int i = 0; i < 4; i++)
      af[i] = *reinterpret_cast<const v8s*>(&sAc[(wm * 64 + i * 16 + lr) * 32 + lg * 8]);
#pragma unroll
    for (int j = 0; j < 4; j++)
      bf[j] = *reinterpret_cast<const v8s*>(&sBc[(wn * 64 + j * 16 + lr) * 32 + lg * 8]);
#pragma unroll
    for (int i = 0; i < 4; i++)
#pragma unroll
      for (int j = 0; j < 4; j++) acc[i][j] = mfma16(af[i], bf[j], acc[i][j]);
    __syncthreads();
  }

#pragma unroll
  for (int i = 0; i < 4; i++) {
#pragma unroll
    for (int j = 0; j < 4; j++) {
      const int gn = n0 + wn * 64 + j * 16 + lr;
      const float bv_ = bias[gn];
#pragma unroll
      for (int r = 0; r < 4; r++) {
        const long gm = m0 + wm * 64 + i * 16 + lg * 4 + r;
        o_f[gm * 512 + gn] = acc[i][j][r] + bv_;
      }
    }
  }
}

// ---------------------------------------------------------------------------
// Fused attention (unchanged from r11).
// ---------------------------------------------------------------------------
__global__ __launch_bounds__(256) void attn_k(
    const unsigned short* __restrict__ qm, const unsigned short* __restrict__ km,
    const unsigned short* __restrict__ vt, float* __restrict__ sc,
    unsigned short* __restrict__ ctx) {
  __shared__ unsigned short sP[32][424];
  __shared__ float redM[2][32], redS[2][32];
  const int t = threadIdx.x;
  const int lane = t & 63, wid = t >> 6;
  const int wq = wid >> 1, wk = wid & 1;
  const int lr = lane & 15, lg = lane >> 4;
  const int bid = blockIdx.x;
  const int orig = (bid & 7) * 2496 + (bid >> 3);
  const int g = orig / 13, qb = orig - g * 13;
  const int bs = g >> 3, h = g & 7;
  const int q0 = qb * 32;
  const long qkb = (long)bs * 204800 + h * 64;

  int qrow = q0 + wq * 16 + lr;
  if (qrow > 399) qrow = 399;
  const v8s aq0 = *reinterpret_cast<const v8s*>(qm + qkb + (long)qrow * 512 + lg * 8);
  const v8s aq1 = *reinterpret_cast<const v8s*>(qm + qkb + (long)qrow * 512 + 32 + lg * 8);

  f32x4 acc[13];
#pragma unroll
  for (int f = 0; f < 13; f++) acc[f] = f32x4{0.f, 0.f, 0.f, 0.f};

#pragma unroll
  for (int f = 0; f < 13; f++) {
    int kr = wk * 208 + f * 16 + lr;
    if (kr > 399) kr = 399;
    const v8s b0 = *reinterpret_cast<const v8s*>(km + qkb + (long)kr * 512 + lg * 8);
    const v8s b1 = *reinterpret_cast<const v8s*>(km + qkb + (long)kr * 512 + 32 + lg * 8);
    acc[f] = mfma16(aq0, b0, acc[f]);
    acc[f] = mfma16(aq1, b1, acc[f]);
  }

  const long sb = ((long)h * 192 + bs) * 160000;
  const int rowb = q0 + wq * 16 + lg * 4;
  const int rloc = wq * 16 + lg * 4;
  float mx[4] = {-3.0e38f, -3.0e38f, -3.0e38f, -3.0e38f};
#pragma unroll
  for (int f = 0; f < 13; f++) {
    const int col = wk * 208 + f * 16 + lr;
#pragma unroll
    for (int r = 0; r < 4; r++) {
      float s = acc[f][r] * 0.125f;
      if (col >= 400) s = -3.0e38f;
      acc[f][r] = s;
      mx[r] = fmaxf(mx[r], s);
      if (col < 400 && rowb + r < 400)
        sc[sb + (long)(rowb + r) * 400 + col] = s;
    }
  }
#pragma unroll
  for (int d = 1; d < 16; d <<= 1)
#pragma unroll
    for (int r = 0; r < 4; r++) mx[r] = fmaxf(mx[r], __shfl_xor(mx[r], d));
  if (lr == 0) {
#pragma unroll
    for (int r = 0; r < 4; r++) redM[wk][rloc + r] = mx[r];
  }
  __syncthreads();

  float M[4], sum[4] = {0.f, 0.f, 0.f, 0.f};
#pragma unroll
  for (int r = 0; r < 4; r++) M[r] = fmaxf(redM[0][rloc + r], redM[1][rloc + r]);
#pragma unroll
  for (int f = 0; f < 13; f++) {
#pragma unroll
    for (int r = 0; r < 4; r++) {
      float p = __expf(acc[f][r] - M[r]);
      sum[r] += p;
      sP[rloc + r][wk * 208 + f * 16 + lr] = f2bf(p);
    }
  }
#pragma unroll
  for (int d = 1; d < 16; d <<= 1)
#pragma unroll
    for (int r = 0; r < 4; r++) sum[r] += __shfl_xor(sum[r], d);
  if (lr == 0) {
#pragma unroll
    for (int r = 0; r < 4; r++) redS[wk][rloc + r] = sum[r];
  }
  __syncthreads();

  float inv[4];
#pragma unroll
  for (int r = 0; r < 4; r++) inv[r] = 1.0f / (redS[0][rloc + r] + redS[1][rloc + r]);

  const long vtb = (long)g * 25600;
  f32x4 o0 = {0.f, 0.f, 0.f, 0.f}, o1 = {0.f, 0.f, 0.f, 0.f};
#pragma unroll
  for (int ks = 0; ks < 13; ks++) {
    const v8s pa = *reinterpret_cast<const v8s*>(&sP[wq * 16 + lr][ks * 32 + lg * 8]);
    const v8s bv0 = *reinterpret_cast<const v8s*>(
        vt + vtb + (long)(wk * 32 + lr) * 400 + ks * 32 + lg * 8);
    const v8s bv1 = *reinterpret_cast<const v8s*>(
        vt + vtb + (long)(wk * 32 + 16 + lr) * 400 + ks * 32 + lg * 8);
    o0 = mfma16(pa, bv0, o0);
    o1 = mfma16(pa, bv1, o1);
  }

  const long cb = (long)bs * 400 * 512 + h * 64 + wk * 32;
#pragma unroll
  for (int r = 0; r < 4; r++) {
    const int row = rowb + r;
    if (row < 400) {
      ctx[cb + (long)row * 512 + lr] = f2bf(o0[r] * inv[r]);
      ctx[cb + (long)row * 512 + 16 + lr] = f2bf(o1[r] * inv[r]);
    }
  }
}

// ---------------------------------------------------------------------------

extern "C" void kernel_launch(void* const* d_in, const int* in_sizes, int n_in,
                              void* d_out, int out_size, void* d_ws, size_t ws_size,
                              hipStream_t stream) {
  (void)in_sizes; (void)n_in; (void)out_size; (void)ws_size;

  const float* query = (const float*)d_in[0];
  const float* key   = (const float*)d_in[1];
  const float* value = (const float*)d_in[2];
  const float* Wq = (const float*)d_in[3];
  const float* bq = (const float*)d_in[4];
  const float* Wk = (const float*)d_in[5];
  const float* bk = (const float*)d_in[6];
  const float* Wv = (const float*)d_in[7];
  const float* bv = (const float*)d_in[8];
  const float* Wo = (const float*)d_in[9];
  const float* bo = (const float*)d_in[10];

  float* out = (float*)d_out;       // 39,321,600 f32
  float* sc  = out + 39321600ULL;   // 245,760,000 f32 (scores)
  float* vhb = sc + 245760000ULL;   // 39,321,600 f32

  char* ws = (char*)d_ws;
  unsigned short* wq_  = (unsigned short*)ws;                   // 78.6 MB
  unsigned short* wk_  = (unsigned short*)(ws + 78643200ULL);   // 78.6 MB
  unsigned short* wvt  = (unsigned short*)(ws + 157286400ULL);  // 78.6 MB
  unsigned short* wW   = (unsigned short*)(ws + 235929600ULL);  // 2 MB
  unsigned short* wctx = wq_;  // safe alias (attn reads Q rect then overwrites)

  dim3 blk(256);

  hipLaunchKernelGGL(cvtw_k, dim3(128, 4), blk, 0, stream, Wq, Wk, Wv, Wo, wW);

  // DIAGNOSTIC: proj and outgemm launched twice (idempotent) for attribution.
  hipLaunchKernelGGL(proj_k, dim3(7200), blk, 0, stream, query, key, value, wW,
                     bq, bk, bv, wq_, wk_, vhb, wvt);
  hipLaunchKernelGGL(proj_k, dim3(7200), blk, 0, stream, query, key, value, wW,
                     bq, bk, bv, wq_, wk_, vhb, wvt);

  hipLaunchKernelGGL(attn_k, dim3(19968), blk, 0, stream, wq_, wk_, wvt, sc, wctx);

  hipLaunchKernelGGL(outgemm_k, dim3(2400), blk, 0, stream, wctx, wW + 786432,
                     bo, out);
  hipLaunchKernelGGL(outgemm_k, dim3(2400), blk, 0, stream, wctx, wW + 786432,
                     bo, out);
}

// Round 13
// 1040.339 us; speedup vs baseline: 1.3991x; 1.3991x over previous
//
#include <hip/hip_runtime.h>

// ---------------------------------------------------------------------------
// AttentionLayer: B=16 S=12 N=400 D=512 H=8 HD=64
// outputs (flat, fp32): out[16,12,400,512] | scores_hb[128,12,400,400]
//                       | v_hb[128,12,400,64]
// NOTE (r3, r9): __builtin_nontemporal_store on these fragment epilogues is a
// ~2x write-cost regression (64B segments, L2 write-merge is load-bearing).
// NOTE (r8): HW v_cvt_pk_bf16_f32 is not RNE — absmax 7.9e-2 fail. Use f2bf.
// NOTE (r11): GEMM K-loops 2-phase double-buffered (one barrier/k-step).
// NOTE (r12 diagnostic): proj ~300us, outgemm ~95us, attn ~650us (61%!),
// cvtw ~10us. proj SQ_LDS_BANK_CONFLICT 1.6e7 (A-stage pitch-32 ds_write
// row-alias + C-tile pitch-136 readback ~8-way).
// NOTE (r13): proj A-pitch 40 / C-pitch 140 (bank floor); attn setprio(T5)
// + 2-deep load pipelines in QK^T and PV.
// ---------------------------------------------------------------------------

typedef float fvec4 __attribute__((ext_vector_type(4)));
typedef float f32x4 __attribute__((ext_vector_type(4)));
typedef unsigned short usvec4 __attribute__((ext_vector_type(4)));
typedef unsigned short usvec8 __attribute__((ext_vector_type(8)));
typedef short v8s __attribute__((ext_vector_type(8)));

#define DEV __device__ __forceinline__

DEV unsigned short f2bf(float f) {
  unsigned int u = __builtin_bit_cast(unsigned int, f);
  u += 0x7FFFu + ((u >> 16) & 1u);  // RNE
  return (unsigned short)(u >> 16);
}

DEV f32x4 mfma16(v8s a, v8s b, f32x4 c) {
  return __builtin_amdgcn_mfma_f32_16x16x32_bf16(a, b, c, 0, 0, 0);
}

DEV void gload16(const void* g, void* l) {
  __builtin_amdgcn_global_load_lds(
      (const __attribute__((address_space(1))) unsigned int*)g,
      (__attribute__((address_space(3))) unsigned int*)l, 16, 0, 0);
}

// all 4 weight matrices (512x512 each) in one launch; blockIdx.y selects
__global__ __launch_bounds__(256) void cvtw_k(const float* __restrict__ w0,
                                              const float* __restrict__ w1,
                                              const float* __restrict__ w2,
                                              const float* __restrict__ w3,
                                              unsigned short* __restrict__ o) {
  const float* w = (blockIdx.y == 0) ? w0 : (blockIdx.y == 1) ? w1
                 : (blockIdx.y == 2) ? w2 : w3;
  unsigned short* op = o + (long)blockIdx.y * 262144;
  long i = ((long)blockIdx.x * 256 + threadIdx.x) * 8;  // grid.x=128 -> exact
  fvec4 a = *reinterpret_cast<const fvec4*>(w + i);
  fvec4 b = *reinterpret_cast<const fvec4*>(w + i + 4);
  usvec8 r;
  r[0] = f2bf(a[0]); r[1] = f2bf(a[1]); r[2] = f2bf(a[2]); r[3] = f2bf(a[3]);
  r[4] = f2bf(b[0]); r[5] = f2bf(b[1]); r[6] = f2bf(b[2]); r[7] = f2bf(b[3]);
  *reinterpret_cast<usvec8*>(op + i) = r;
}

// ---------------------------------------------------------------------------
// Merged projection GEMM (q,k,v in ONE launch; grid 7200 = 8*900 XCD-chunked).
// 2-phase dbuf; A fp32 reg-staged cvt (pitch 40 = bank floor); B gload16
// (linear pitch 32). C-tile epilogue pitch 140 (bank floor).
// LDS shorts: A bufs [0,5120),[5120,10240); B bufs [10240,14336),[14336,18432)
// C-tile overlays [0, 17920).
// ---------------------------------------------------------------------------
__global__ __launch_bounds__(256) void proj_k(
    const float* __restrict__ qin, const float* __restrict__ kin,
    const float* __restrict__ vin, const unsigned short* __restrict__ wW,
    const float* __restrict__ bqp, const float* __restrict__ bkp,
    const float* __restrict__ bvp, unsigned short* __restrict__ wq_,
    unsigned short* __restrict__ wk_, float* __restrict__ vhb,
    unsigned short* __restrict__ wvt) {
  __shared__ unsigned short sMem[18432];
  const int t = threadIdx.x;
  const int lane = t & 63, wid = t >> 6;
  const int wm = wid >> 1, wn = wid & 1;
  const int lr = lane & 15, lg = lane >> 4;
  const int bid = blockIdx.x;
  const int orig = (bid & 7) * 900 + (bid >> 3);
  const int which = orig >= 4800 ? 2 : (orig >= 2400 ? 1 : 0);
  const int inner = orig - which * 2400;
  const long m0 = (long)(inner >> 2) * 128;
  const int n0 = (inner & 3) * 128;

  const float* A = which == 0 ? qin : which == 1 ? kin : vin;
  const unsigned short* W = wW + (long)which * 262144;
  const float* bias = which == 0 ? bqp : which == 1 ? bkp : bvp;

  const int srow = wid * 16 + (lane >> 2);
  const int scol = (lane & 3) * 8;
  const unsigned short* bS0 = W + (long)(n0 + srow) * 512 + scol;
  const unsigned short* bS1 = bS0 + 64 * 512;
  const int bOff0 = wid * 512;
  const int bOff1 = (wid + 4) * 512;

  const int arow = t >> 3;       // 0..31
  const int acol = (t & 7) * 4;  // f32 col within k-tile
  const float* aP32 = A + (m0 + arow) * 512 + acol;
  const int aOff = arow * 40 + acol;  // pitch 40 shorts (80B) = bank floor

  f32x4 acc[4][4] = {};
  fvec4 aReg[4];
#pragma unroll
  for (int i = 0; i < 4; i++)
    aReg[i] = *reinterpret_cast<const fvec4*>(aP32 + (long)i * 16384);

  {  // prologue: stage tile 0 into buf0, prefetch A regs for tile 1
    unsigned short* sA0 = sMem;
    unsigned short* sB0 = sMem + 10240;
    gload16(bS0, sB0 + bOff0);
    gload16(bS1, sB0 + bOff1);
#pragma unroll
    for (int i = 0; i < 4; i++) {
      usvec4 pk;
      pk[0] = f2bf(aReg[i][0]); pk[1] = f2bf(aReg[i][1]);
      pk[2] = f2bf(aReg[i][2]); pk[3] = f2bf(aReg[i][3]);
      *reinterpret_cast<usvec4*>(sA0 + aOff + i * 1280) = pk;  // 32 rows * 40
    }
#pragma unroll
    for (int i = 0; i < 4; i++)
      aReg[i] = *reinterpret_cast<const fvec4*>(aP32 + (long)i * 16384 + 32);
  }
  __syncthreads();

  for (int k0 = 0; k0 < 512; k0 += 32) {
    const int c = (k0 >> 5) & 1;
    unsigned short* sAc = sMem + c * 5120;
    unsigned short* sBc = sMem + 10240 + c * 4096;
    if (k0 < 480) {  // stage tile k0+32 into buf^1
      unsigned short* sAn = sMem + (c ^ 1) * 5120;
      unsigned short* sBn = sMem + 10240 + (c ^ 1) * 4096;
      gload16(bS0 + k0 + 32, sBn + bOff0);
      gload16(bS1 + k0 + 32, sBn + bOff1);
#pragma unroll
      for (int i = 0; i < 4; i++) {
        usvec4 pk;
        pk[0] = f2bf(aReg[i][0]); pk[1] = f2bf(aReg[i][1]);
        pk[2] = f2bf(aReg[i][2]); pk[3] = f2bf(aReg[i][3]);
        *reinterpret_cast<usvec4*>(sAn + aOff + i * 1280) = pk;
      }
      if (k0 < 448) {
#pragma unroll
        for (int i = 0; i < 4; i++)
          aReg[i] = *reinterpret_cast<const fvec4*>(aP32 + (long)i * 16384 +
                                                    k0 + 64);
      }
    }

    v8s af[4], bf[4];
#pragma unroll
    for (int i = 0; i < 4; i++)
      af[i] = *reinterpret_cast<const v8s*>(&sAc[(wm * 64 + i * 16 + lr) * 40 + lg * 8]);
#pragma unroll
    for (int j = 0; j < 4; j++)
      bf[j] = *reinterpret_cast<const v8s*>(&sBc[(wn * 64 + j * 16 + lr) * 32 + lg * 8]);
    __builtin_amdgcn_s_setprio(1);
#pragma unroll
    for (int i = 0; i < 4; i++)
#pragma unroll
      for (int j = 0; j < 4; j++) acc[i][j] = mfma16(af[i], bf[j], acc[i][j]);
    __builtin_amdgcn_s_setprio(0);
    __syncthreads();
  }

  if (which <= 1) {
    unsigned short* o_h = which == 0 ? wq_ : wk_;
    // stage C tile (bf16, +bias) in LDS (pitch 140), coalesced 64B stores
#pragma unroll
    for (int i = 0; i < 4; i++) {
#pragma unroll
      for (int j = 0; j < 4; j++) {
        const int col = wn * 64 + j * 16 + lr;
        const float bv_ = bias[n0 + col];
#pragma unroll
        for (int r = 0; r < 4; r++) {
          const int row = wm * 64 + i * 16 + lg * 4 + r;
          sMem[row * 140 + col] = f2bf(acc[i][j][r] + bv_);
        }
      }
    }
    __syncthreads();
#pragma unroll
    for (int pass = 0; pass < 2; pass++) {
      const int row = (t >> 2) + pass * 64;
      const int c0 = (t & 3) * 8;
      const unsigned short* src = &sMem[row * 140 + c0];
      unsigned short* dst = &o_h[(m0 + row) * 512 + n0 + c0];
#pragma unroll
      for (int k = 0; k < 4; k++)
        *reinterpret_cast<usvec8*>(dst + k * 32) =
            *reinterpret_cast<const usvec8*>(src + k * 32);
    }
  } else {
#pragma unroll
    for (int i = 0; i < 4; i++) {
#pragma unroll
      for (int j = 0; j < 4; j++) {
        const int gn = n0 + wn * 64 + j * 16 + lr;
        const float bv_ = bias[gn];
        const long gm0 = m0 + wm * 64 + i * 16 + lg * 4;
        const int bs_lin = (int)(gm0 / 400);
        const int node0 = (int)(gm0 - (long)bs_lin * 400);
        const int h = gn >> 6, hd = gn & 63;
        float* vp = vhb + ((((long)(h * 192 + bs_lin) * 400 + node0) << 6) + hd);
        const float v0 = acc[i][j][0] + bv_, v1 = acc[i][j][1] + bv_;
        const float v2 = acc[i][j][2] + bv_, v3 = acc[i][j][3] + bv_;
        vp[0] = v0;
        vp[64] = v1;
        vp[128] = v2;
        vp[192] = v3;
        usvec4 pk;
        pk[0] = f2bf(v0); pk[1] = f2bf(v1); pk[2] = f2bf(v2); pk[3] = f2bf(v3);
        *reinterpret_cast<usvec4*>(
            wvt + (((long)(bs_lin * 8 + h) * 64 + hd) * 400 + node0)) = pk;
      }
    }
  }
}

// ---------------------------------------------------------------------------
// Output GEMM: 2-phase dbuf, gload16 A and B (linear 32-pitch = read floor).
// ---------------------------------------------------------------------------
__global__ __launch_bounds__(256) void outgemm_k(
    const unsigned short* __restrict__ A, const unsigned short* __restrict__ W,
    const float* __restrict__ bias, float* __restrict__ o_f) {
  __shared__ unsigned short sMem[16384];
  const int t = threadIdx.x;
  const int lane = t & 63, wid = t >> 6;
  const int wm = wid >> 1, wn = wid & 1;
  const int lr = lane & 15, lg = lane >> 4;
  const int bid = blockIdx.x;
  const int orig = (bid & 7) * 300 + (bid >> 3);
  const long m0 = (long)(orig >> 2) * 128;
  const int n0 = (orig & 3) * 128;

  const int srow = wid * 16 + (lane >> 2);
  const int scol = (lane & 3) * 8;
  const unsigned short* aS0 = A + (m0 + srow) * 512 + scol;
  const unsigned short* aS1 = aS0 + 64 * 512;
  const unsigned short* bS0 = W + (long)(n0 + srow) * 512 + scol;
  const unsigned short* bS1 = bS0 + 64 * 512;
  const int bOff0 = wid * 512;
  const int bOff1 = (wid + 4) * 512;

  f32x4 acc[4][4] = {};

  {
    gload16(aS0, sMem + bOff0);
    gload16(aS1, sMem + bOff1);
    gload16(bS0, sMem + 8192 + bOff0);
    gload16(bS1, sMem + 8192 + bOff1);
  }
  __syncthreads();

  for (int k0 = 0; k0 < 512; k0 += 32) {
    const int c = (k0 >> 5) & 1;
    unsigned short* sAc = sMem + c * 4096;
    unsigned short* sBc = sMem + 8192 + c * 4096;
    if (k0 < 480) {
      unsigned short* sAn = sMem + (c ^ 1) * 4096;
      unsigned short* sBn = sMem + 8192 + (c ^ 1) * 4096;
      gload16(aS0 + k0 + 32, sAn + bOff0);
      gload16(aS1 + k0 + 32, sAn + bOff1);
      gload16(bS0 + k0 + 32, sBn + bOff0);
      gload16(bS1 + k0 + 32, sBn + bOff1);
    }

    v8s af[4], bf[4];
#pragma unroll
    for (int i = 0; i < 4; i++)
      af[i] = *reinterpret_cast<const v8s*>(&sAc[(wm * 64 + i * 16 + lr) * 32 + lg * 8]);
#pragma unroll
    for (int j = 0; j < 4; j++)
      bf[j] = *reinterpret_cast<const v8s*>(&sBc[(wn * 64 + j * 16 + lr) * 32 + lg * 8]);
    __builtin_amdgcn_s_setprio(1);
#pragma unroll
    for (int i = 0; i < 4; i++)
#pragma unroll
      for (int j = 0; j < 4; j++) acc[i][j] = mfma16(af[i], bf[j], acc[i][j]);
    __builtin_amdgcn_s_setprio(0);
    __syncthreads();
  }

#pragma unroll
  for (int i = 0; i < 4; i++) {
#pragma unroll
    for (int j = 0; j < 4; j++) {
      const int gn = n0 + wn * 64 + j * 16 + lr;
      const float bv_ = bias[gn];
#pragma unroll
      for (int r = 0; r < 4; r++) {
        const long gm = m0 + wm * 64 + i * 16 + lg * 4 + r;
        o_f[gm * 512 + gn] = acc[i][j][r] + bv_;
      }
    }
  }
}

// ---------------------------------------------------------------------------
// Fused attention: per block = one (bs,h) group x 32 q-rows.
// r13: setprio(T5, m191 attn-proven) + 2-deep load pipelines in QK^T and PV.
// 1D grid 19968 (= 8*2496), XCD-chunked swizzle, qb fastest (K/V L2 reuse).
// ---------------------------------------------------------------------------
__global__ __launch_bounds__(256) void attn_k(
    const unsigned short* __restrict__ qm, const unsigned short* __restrict__ km,
    const unsigned short* __restrict__ vt, float* __restrict__ sc,
    unsigned short* __restrict__ ctx) {
  __shared__ unsigned short sP[32][424];
  __shared__ float redM[2][32], redS[2][32];
  const int t = threadIdx.x;
  const int lane = t & 63, wid = t >> 6;
  const int wq = wid >> 1, wk = wid & 1;
  const int lr = lane & 15, lg = lane >> 4;
  const int bid = blockIdx.x;
  const int orig = (bid & 7) * 2496 + (bid >> 3);
  const int g = orig / 13, qb = orig - g * 13;
  const int bs = g >> 3, h = g & 7;
  const int q0 = qb * 32;
  const long qkb = (long)bs * 204800 + h * 64;

  int qrow = q0 + wq * 16 + lr;
  if (qrow > 399) qrow = 399;
  const v8s aq0 = *reinterpret_cast<const v8s*>(qm + qkb + (long)qrow * 512 + lg * 8);
  const v8s aq1 = *reinterpret_cast<const v8s*>(qm + qkb + (long)qrow * 512 + 32 + lg * 8);

  f32x4 acc[13];
#pragma unroll
  for (int f = 0; f < 13; f++) acc[f] = f32x4{0.f, 0.f, 0.f, 0.f};

  // QK^T: 2-deep pipeline, setprio around MFMA pair
  {
    int kr0 = wk * 208 + lr;
    if (kr0 > 399) kr0 = 399;
    v8s b0 = *reinterpret_cast<const v8s*>(km + qkb + (long)kr0 * 512 + lg * 8);
    v8s b1 = *reinterpret_cast<const v8s*>(km + qkb + (long)kr0 * 512 + 32 + lg * 8);
#pragma unroll
    for (int f = 0; f < 13; f++) {
      v8s nb0 = b0, nb1 = b1;
      if (f < 12) {
        int kr = wk * 208 + (f + 1) * 16 + lr;
        if (kr > 399) kr = 399;
        nb0 = *reinterpret_cast<const v8s*>(km + qkb + (long)kr * 512 + lg * 8);
        nb1 = *reinterpret_cast<const v8s*>(km + qkb + (long)kr * 512 + 32 + lg * 8);
      }
      __builtin_amdgcn_s_setprio(1);
      acc[f] = mfma16(aq0, b0, acc[f]);
      acc[f] = mfma16(aq1, b1, acc[f]);
      __builtin_amdgcn_s_setprio(0);
      b0 = nb0;
      b1 = nb1;
    }
  }

  const long sb = ((long)h * 192 + bs) * 160000;
  const int rowb = q0 + wq * 16 + lg * 4;
  const int rloc = wq * 16 + lg * 4;
  float mx[4] = {-3.0e38f, -3.0e38f, -3.0e38f, -3.0e38f};
#pragma unroll
  for (int f = 0; f < 13; f++) {
    const int col = wk * 208 + f * 16 + lr;
#pragma unroll
    for (int r = 0; r < 4; r++) {
      float s = acc[f][r] * 0.125f;
      if (col >= 400) s = -3.0e38f;
      acc[f][r] = s;
      mx[r] = fmaxf(mx[r], s);
      if (col < 400 && rowb + r < 400)
        sc[sb + (long)(rowb + r) * 400 + col] = s;
    }
  }
#pragma unroll
  for (int d = 1; d < 16; d <<= 1)
#pragma unroll
    for (int r = 0; r < 4; r++) mx[r] = fmaxf(mx[r], __shfl_xor(mx[r], d));
  if (lr == 0) {
#pragma unroll
    for (int r = 0; r < 4; r++) redM[wk][rloc + r] = mx[r];
  }
  __syncthreads();

  float M[4], sum[4] = {0.f, 0.f, 0.f, 0.f};
#pragma unroll
  for (int r = 0; r < 4; r++) M[r] = fmaxf(redM[0][rloc + r], redM[1][rloc + r]);
#pragma unroll
  for (int f = 0; f < 13; f++) {
#pragma unroll
    for (int r = 0; r < 4; r++) {
      float p = __expf(acc[f][r] - M[r]);
      sum[r] += p;
      sP[rloc + r][wk * 208 + f * 16 + lr] = f2bf(p);
    }
  }
#pragma unroll
  for (int d = 1; d < 16; d <<= 1)
#pragma unroll
    for (int r = 0; r < 4; r++) sum[r] += __shfl_xor(sum[r], d);
  if (lr == 0) {
#pragma unroll
    for (int r = 0; r < 4; r++) redS[wk][rloc + r] = sum[r];
  }
  __syncthreads();

  float inv[4];
#pragma unroll
  for (int r = 0; r < 4; r++) inv[r] = 1.0f / (redS[0][rloc + r] + redS[1][rloc + r]);

  // PV: 2-deep pipeline (sP ds_read + 2 global V loads ahead), setprio on MFMA
  const long vtb = (long)g * 25600;
  const unsigned short* vrow0 = vt + vtb + (long)(wk * 32 + lr) * 400;
  const unsigned short* vrow1 = vt + vtb + (long)(wk * 32 + 16 + lr) * 400;
  f32x4 o0 = {0.f, 0.f, 0.f, 0.f}, o1 = {0.f, 0.f, 0.f, 0.f};
  {
    v8s pa = *reinterpret_cast<const v8s*>(&sP[wq * 16 + lr][lg * 8]);
    v8s bv0 = *reinterpret_cast<const v8s*>(vrow0 + lg * 8);
    v8s bv1 = *reinterpret_cast<const v8s*>(vrow1 + lg * 8);
#pragma unroll
    for (int ks = 0; ks < 13; ks++) {
      v8s npa = pa, nbv0 = bv0, nbv1 = bv1;
      if (ks < 12) {
        npa = *reinterpret_cast<const v8s*>(&sP[wq * 16 + lr][(ks + 1) * 32 + lg * 8]);
        nbv0 = *reinterpret_cast<const v8s*>(vrow0 + (ks + 1) * 32 + lg * 8);
        nbv1 = *reinterpret_cast<const v8s*>(vrow1 + (ks + 1) * 32 + lg * 8);
      }
      __builtin_amdgcn_s_setprio(1);
      o0 = mfma16(pa, bv0, o0);
      o1 = mfma16(pa, bv1, o1);
      __builtin_amdgcn_s_setprio(0);
      pa = npa;
      bv0 = nbv0;
      bv1 = nbv1;
    }
  }

  const long cb = (long)bs * 400 * 512 + h * 64 + wk * 32;
#pragma unroll
  for (int r = 0; r < 4; r++) {
    const int row = rowb + r;
    if (row < 400) {
      ctx[cb + (long)row * 512 + lr] = f2bf(o0[r] * inv[r]);
      ctx[cb + (long)row * 512 + 16 + lr] = f2bf(o1[r] * inv[r]);
    }
  }
}

// ---------------------------------------------------------------------------

extern "C" void kernel_launch(void* const* d_in, const int* in_sizes, int n_in,
                              void* d_out, int out_size, void* d_ws, size_t ws_size,
                              hipStream_t stream) {
  (void)in_sizes; (void)n_in; (void)out_size; (void)ws_size;

  const float* query = (const float*)d_in[0];
  const float* key   = (const float*)d_in[1];
  const float* value = (const float*)d_in[2];
  const float* Wq = (const float*)d_in[3];
  const float* bq = (const float*)d_in[4];
  const float* Wk = (const float*)d_in[5];
  const float* bk = (const float*)d_in[6];
  const float* Wv = (const float*)d_in[7];
  const float* bv = (const float*)d_in[8];
  const float* Wo = (const float*)d_in[9];
  const float* bo = (const float*)d_in[10];

  float* out = (float*)d_out;       // 39,321,600 f32
  float* sc  = out + 39321600ULL;   // 245,760,000 f32 (scores)
  float* vhb = sc + 245760000ULL;   // 39,321,600 f32

  char* ws = (char*)d_ws;
  unsigned short* wq_  = (unsigned short*)ws;                   // 78.6 MB
  unsigned short* wk_  = (unsigned short*)(ws + 78643200ULL);   // 78.6 MB
  unsigned short* wvt  = (unsigned short*)(ws + 157286400ULL);  // 78.6 MB
  unsigned short* wW   = (unsigned short*)(ws + 235929600ULL);  // 2 MB
  unsigned short* wctx = wq_;  // safe alias (attn reads Q rect then overwrites)

  dim3 blk(256);

  hipLaunchKernelGGL(cvtw_k, dim3(128, 4), blk, 0, stream, Wq, Wk, Wv, Wo, wW);

  hipLaunchKernelGGL(proj_k, dim3(7200), blk, 0, stream, query, key, value, wW,
                     bq, bk, bv, wq_, wk_, vhb, wvt);

  hipLaunchKernelGGL(attn_k, dim3(19968), blk, 0, stream, wq_, wk_, wvt, sc, wctx);

  hipLaunchKernelGGL(outgemm_k, dim3(2400), blk, 0, stream, wctx, wW + 786432,
                     bo, out);
}

// Round 15
// 1026.400 us; speedup vs baseline: 1.4181x; 1.0136x over previous
//
#include <hip/hip_runtime.h>

// ---------------------------------------------------------------------------
// AttentionLayer: B=16 S=12 N=400 D=512 H=8 HD=64
// outputs (flat, fp32): out[16,12,400,512] | scores_hb[128,12,400,400]
//                       | v_hb[128,12,400,64]
// NOTE (r3, r9): __builtin_nontemporal_store on these fragment epilogues is a
// ~2x write-cost regression (64B segments, L2 write-merge is load-bearing).
// NOTE (r8): HW v_cvt_pk_bf16_f32 is not RNE — absmax 7.9e-2 fail. Use f2bf.
// NOTE (r11): GEMM K-loops 2-phase double-buffered (one barrier/k-step).
// NOTE (r12 diagnostic): proj ~300us, outgemm ~95us, attn ~650us, cvtw ~10us.
// NOTE (r13): proj A-pitch 40 / C-pitch 140 (bank floor); setprio on MFMA.
// NOTE (r14): attn sc-store fusion caused REPLAY-ONLY divergence on scores
// (first call passed) — race signature. Reverted to r13 attn; the one latent
// race candidate (wctx aliasing wq_) is now removed when ws_size permits a
// separate ctx buffer (deterministic: ws_size is constant per run).
// ---------------------------------------------------------------------------

typedef float fvec4 __attribute__((ext_vector_type(4)));
typedef float f32x4 __attribute__((ext_vector_type(4)));
typedef unsigned short usvec4 __attribute__((ext_vector_type(4)));
typedef unsigned short usvec8 __attribute__((ext_vector_type(8)));
typedef short v8s __attribute__((ext_vector_type(8)));

#define DEV __device__ __forceinline__

DEV unsigned short f2bf(float f) {
  unsigned int u = __builtin_bit_cast(unsigned int, f);
  u += 0x7FFFu + ((u >> 16) & 1u);  // RNE
  return (unsigned short)(u >> 16);
}

DEV f32x4 mfma16(v8s a, v8s b, f32x4 c) {
  return __builtin_amdgcn_mfma_f32_16x16x32_bf16(a, b, c, 0, 0, 0);
}

DEV void gload16(const void* g, void* l) {
  __builtin_amdgcn_global_load_lds(
      (const __attribute__((address_space(1))) unsigned int*)g,
      (__attribute__((address_space(3))) unsigned int*)l, 16, 0, 0);
}

// all 4 weight matrices (512x512 each) in one launch; blockIdx.y selects
__global__ __launch_bounds__(256) void cvtw_k(const float* __restrict__ w0,
                                              const float* __restrict__ w1,
                                              const float* __restrict__ w2,
                                              const float* __restrict__ w3,
                                              unsigned short* __restrict__ o) {
  const float* w = (blockIdx.y == 0) ? w0 : (blockIdx.y == 1) ? w1
                 : (blockIdx.y == 2) ? w2 : w3;
  unsigned short* op = o + (long)blockIdx.y * 262144;
  long i = ((long)blockIdx.x * 256 + threadIdx.x) * 8;  // grid.x=128 -> exact
  fvec4 a = *reinterpret_cast<const fvec4*>(w + i);
  fvec4 b = *reinterpret_cast<const fvec4*>(w + i + 4);
  usvec8 r;
  r[0] = f2bf(a[0]); r[1] = f2bf(a[1]); r[2] = f2bf(a[2]); r[3] = f2bf(a[3]);
  r[4] = f2bf(b[0]); r[5] = f2bf(b[1]); r[6] = f2bf(b[2]); r[7] = f2bf(b[3]);
  *reinterpret_cast<usvec8*>(op + i) = r;
}

// ---------------------------------------------------------------------------
// Merged projection GEMM (q,k,v in ONE launch; grid 7200 = 8*900 XCD-chunked).
// 2-phase dbuf; A fp32 reg-staged cvt (pitch 40 = bank floor); B gload16
// (linear pitch 32). C-tile epilogue pitch 140 (bank floor).
// ---------------------------------------------------------------------------
__global__ __launch_bounds__(256) void proj_k(
    const float* __restrict__ qin, const float* __restrict__ kin,
    const float* __restrict__ vin, const unsigned short* __restrict__ wW,
    const float* __restrict__ bqp, const float* __restrict__ bkp,
    const float* __restrict__ bvp, unsigned short* __restrict__ wq_,
    unsigned short* __restrict__ wk_, float* __restrict__ vhb,
    unsigned short* __restrict__ wvt) {
  __shared__ unsigned short sMem[18432];
  const int t = threadIdx.x;
  const int lane = t & 63, wid = t >> 6;
  const int wm = wid >> 1, wn = wid & 1;
  const int lr = lane & 15, lg = lane >> 4;
  const int bid = blockIdx.x;
  const int orig = (bid & 7) * 900 + (bid >> 3);
  const int which = orig >= 4800 ? 2 : (orig >= 2400 ? 1 : 0);
  const int inner = orig - which * 2400;
  const long m0 = (long)(inner >> 2) * 128;
  const int n0 = (inner & 3) * 128;

  const float* A = which == 0 ? qin : which == 1 ? kin : vin;
  const unsigned short* W = wW + (long)which * 262144;
  const float* bias = which == 0 ? bqp : which == 1 ? bkp : bvp;

  const int srow = wid * 16 + (lane >> 2);
  const int scol = (lane & 3) * 8;
  const unsigned short* bS0 = W + (long)(n0 + srow) * 512 + scol;
  const unsigned short* bS1 = bS0 + 64 * 512;
  const int bOff0 = wid * 512;
  const int bOff1 = (wid + 4) * 512;

  const int arow = t >> 3;       // 0..31
  const int acol = (t & 7) * 4;  // f32 col within k-tile
  const float* aP32 = A + (m0 + arow) * 512 + acol;
  const int aOff = arow * 40 + acol;  // pitch 40 shorts (80B) = bank floor

  f32x4 acc[4][4] = {};
  fvec4 aReg[4];
#pragma unroll
  for (int i = 0; i < 4; i++)
    aReg[i] = *reinterpret_cast<const fvec4*>(aP32 + (long)i * 16384);

  {  // prologue: stage tile 0 into buf0, prefetch A regs for tile 1
    unsigned short* sA0 = sMem;
    unsigned short* sB0 = sMem + 10240;
    gload16(bS0, sB0 + bOff0);
    gload16(bS1, sB0 + bOff1);
#pragma unroll
    for (int i = 0; i < 4; i++) {
      usvec4 pk;
      pk[0] = f2bf(aReg[i][0]); pk[1] = f2bf(aReg[i][1]);
      pk[2] = f2bf(aReg[i][2]); pk[3] = f2bf(aReg[i][3]);
      *reinterpret_cast<usvec4*>(sA0 + aOff + i * 1280) = pk;  // 32 rows * 40
    }
#pragma unroll
    for (int i = 0; i < 4; i++)
      aReg[i] = *reinterpret_cast<const fvec4*>(aP32 + (long)i * 16384 + 32);
  }
  __syncthreads();

  for (int k0 = 0; k0 < 512; k0 += 32) {
    const int c = (k0 >> 5) & 1;
    unsigned short* sAc = sMem + c * 5120;
    unsigned short* sBc = sMem + 10240 + c * 4096;
    if (k0 < 480) {  // stage tile k0+32 into buf^1
      unsigned short* sAn = sMem + (c ^ 1) * 5120;
      unsigned short* sBn = sMem + 10240 + (c ^ 1) * 4096;
      gload16(bS0 + k0 + 32, sBn + bOff0);
      gload16(bS1 + k0 + 32, sBn + bOff1);
#pragma unroll
      for (int i = 0; i < 4; i++) {
        usvec4 pk;
        pk[0] = f2bf(aReg[i][0]); pk[1] = f2bf(aReg[i][1]);
        pk[2] = f2bf(aReg[i][2]); pk[3] = f2bf(aReg[i][3]);
        *reinterpret_cast<usvec4*>(sAn + aOff + i * 1280) = pk;
      }
      if (k0 < 448) {
#pragma unroll
        for (int i = 0; i < 4; i++)
          aReg[i] = *reinterpret_cast<const fvec4*>(aP32 + (long)i * 16384 +
                                                    k0 + 64);
      }
    }

    v8s af[4], bf[4];
#pragma unroll
    for (int i = 0; i < 4; i++)
      af[i] = *reinterpret_cast<const v8s*>(&sAc[(wm * 64 + i * 16 + lr) * 40 + lg * 8]);
#pragma unroll
    for (int j = 0; j < 4; j++)
      bf[j] = *reinterpret_cast<const v8s*>(&sBc[(wn * 64 + j * 16 + lr) * 32 + lg * 8]);
    __builtin_amdgcn_s_setprio(1);
#pragma unroll
    for (int i = 0; i < 4; i++)
#pragma unroll
      for (int j = 0; j < 4; j++) acc[i][j] = mfma16(af[i], bf[j], acc[i][j]);
    __builtin_amdgcn_s_setprio(0);
    __syncthreads();
  }

  if (which <= 1) {
    unsigned short* o_h = which == 0 ? wq_ : wk_;
    // stage C tile (bf16, +bias) in LDS (pitch 140), coalesced 64B stores
#pragma unroll
    for (int i = 0; i < 4; i++) {
#pragma unroll
      for (int j = 0; j < 4; j++) {
        const int col = wn * 64 + j * 16 + lr;
        const float bv_ = bias[n0 + col];
#pragma unroll
        for (int r = 0; r < 4; r++) {
          const int row = wm * 64 + i * 16 + lg * 4 + r;
          sMem[row * 140 + col] = f2bf(acc[i][j][r] + bv_);
        }
      }
    }
    __syncthreads();
#pragma unroll
    for (int pass = 0; pass < 2; pass++) {
      const int row = (t >> 2) + pass * 64;
      const int c0 = (t & 3) * 8;
      const unsigned short* src = &sMem[row * 140 + c0];
      unsigned short* dst = &o_h[(m0 + row) * 512 + n0 + c0];
#pragma unroll
      for (int k = 0; k < 4; k++)
        *reinterpret_cast<usvec8*>(dst + k * 32) =
            *reinterpret_cast<const usvec8*>(src + k * 32);
    }
  } else {
#pragma unroll
    for (int i = 0; i < 4; i++) {
#pragma unroll
      for (int j = 0; j < 4; j++) {
        const int gn = n0 + wn * 64 + j * 16 + lr;
        const float bv_ = bias[gn];
        const long gm0 = m0 + wm * 64 + i * 16 + lg * 4;
        const int bs_lin = (int)(gm0 / 400);
        const int node0 = (int)(gm0 - (long)bs_lin * 400);
        const int h = gn >> 6, hd = gn & 63;
        float* vp = vhb + ((((long)(h * 192 + bs_lin) * 400 + node0) << 6) + hd);
        const float v0 = acc[i][j][0] + bv_, v1 = acc[i][j][1] + bv_;
        const float v2 = acc[i][j][2] + bv_, v3 = acc[i][j][3] + bv_;
        vp[0] = v0;
        vp[64] = v1;
        vp[128] = v2;
        vp[192] = v3;
        usvec4 pk;
        pk[0] = f2bf(v0); pk[1] = f2bf(v1); pk[2] = f2bf(v2); pk[3] = f2bf(v3);
        *reinterpret_cast<usvec4*>(
            wvt + (((long)(bs_lin * 8 + h) * 64 + hd) * 400 + node0)) = pk;
      }
    }
  }
}

// ---------------------------------------------------------------------------
// Output GEMM: 2-phase dbuf, gload16 A and B (linear 32-pitch = read floor).
// ---------------------------------------------------------------------------
__global__ __launch_bounds__(256) void outgemm_k(
    const unsigned short* __restrict__ A, const unsigned short* __restrict__ W,
    const float* __restrict__ bias, float* __restrict__ o_f) {
  __shared__ unsigned short sMem[16384];
  const int t = threadIdx.x;
  const int lane = t & 63, wid = t >> 6;
  const int wm = wid >> 1, wn = wid & 1;
  const int lr = lane & 15, lg = lane >> 4;
  const int bid = blockIdx.x;
  const int orig = (bid & 7) * 300 + (bid >> 3);
  const long m0 = (long)(orig >> 2) * 128;
  const int n0 = (orig & 3) * 128;

  const int srow = wid * 16 + (lane >> 2);
  const int scol = (lane & 3) * 8;
  const unsigned short* aS0 = A + (m0 + srow) * 512 + scol;
  const unsigned short* aS1 = aS0 + 64 * 512;
  const unsigned short* bS0 = W + (long)(n0 + srow) * 512 + scol;
  const unsigned short* bS1 = bS0 + 64 * 512;
  const int bOff0 = wid * 512;
  const int bOff1 = (wid + 4) * 512;

  f32x4 acc[4][4] = {};

  {
    gload16(aS0, sMem + bOff0);
    gload16(aS1, sMem + bOff1);
    gload16(bS0, sMem + 8192 + bOff0);
    gload16(bS1, sMem + 8192 + bOff1);
  }
  __syncthreads();

  for (int k0 = 0; k0 < 512; k0 += 32) {
    const int c = (k0 >> 5) & 1;
    unsigned short* sAc = sMem + c * 4096;
    unsigned short* sBc = sMem + 8192 + c * 4096;
    if (k0 < 480) {
      unsigned short* sAn = sMem + (c ^ 1) * 4096;
      unsigned short* sBn = sMem + 8192 + (c ^ 1) * 4096;
      gload16(aS0 + k0 + 32, sAn + bOff0);
      gload16(aS1 + k0 + 32, sAn + bOff1);
      gload16(bS0 + k0 + 32, sBn + bOff0);
      gload16(bS1 + k0 + 32, sBn + bOff1);
    }

    v8s af[4], bf[4];
#pragma unroll
    for (int i = 0; i < 4; i++)
      af[i] = *reinterpret_cast<const v8s*>(&sAc[(wm * 64 + i * 16 + lr) * 32 + lg * 8]);
#pragma unroll
    for (int j = 0; j < 4; j++)
      bf[j] = *reinterpret_cast<const v8s*>(&sBc[(wn * 64 + j * 16 + lr) * 32 + lg * 8]);
    __builtin_amdgcn_s_setprio(1);
#pragma unroll
    for (int i = 0; i < 4; i++)
#pragma unroll
      for (int j = 0; j < 4; j++) acc[i][j] = mfma16(af[i], bf[j], acc[i][j]);
    __builtin_amdgcn_s_setprio(0);
    __syncthreads();
  }

#pragma unroll
  for (int i = 0; i < 4; i++) {
#pragma unroll
    for (int j = 0; j < 4; j++) {
      const int gn = n0 + wn * 64 + j * 16 + lr;
      const float bv_ = bias[gn];
#pragma unroll
      for (int r = 0; r < 4; r++) {
        const long gm = m0 + wm * 64 + i * 16 + lg * 4 + r;
        o_f[gm * 512 + gn] = acc[i][j][r] + bv_;
      }
    }
  }
}

// ---------------------------------------------------------------------------
// Fused attention (r13 version, byte-identical): setprio + 2-deep pipelines.
// 1D grid 19968 (= 8*2496), XCD-chunked swizzle, qb fastest (K/V L2 reuse).
// ---------------------------------------------------------------------------
__global__ __launch_bounds__(256) void attn_k(
    const unsigned short* __restrict__ qm, const unsigned short* __restrict__ km,
    const unsigned short* __restrict__ vt, float* __restrict__ sc,
    unsigned short* __restrict__ ctx) {
  __shared__ unsigned short sP[32][424];
  __shared__ float redM[2][32], redS[2][32];
  const int t = threadIdx.x;
  const int lane = t & 63, wid = t >> 6;
  const int wq = wid >> 1, wk = wid & 1;
  const int lr = lane & 15, lg = lane >> 4;
  const int bid = blockIdx.x;
  const int orig = (bid & 7) * 2496 + (bid >> 3);
  const int g = orig / 13, qb = orig - g * 13;
  const int bs = g >> 3, h = g & 7;
  const int q0 = qb * 32;
  const long qkb = (long)bs * 204800 + h * 64;

  int qrow = q0 + wq * 16 + lr;
  if (qrow > 399) qrow = 399;
  const v8s aq0 = *reinterpret_cast<const v8s*>(qm + qkb + (long)qrow * 512 + lg * 8);
  const v8s aq1 = *reinterpret_cast<const v8s*>(qm + qkb + (long)qrow * 512 + 32 + lg * 8);

  f32x4 acc[13];
#pragma unroll
  for (int f = 0; f < 13; f++) acc[f] = f32x4{0.f, 0.f, 0.f, 0.f};

  // QK^T: 2-deep pipeline, setprio around MFMA pair
  {
    int kr0 = wk * 208 + lr;
    if (kr0 > 399) kr0 = 399;
    v8s b0 = *reinterpret_cast<const v8s*>(km + qkb + (long)kr0 * 512 + lg * 8);
    v8s b1 = *reinterpret_cast<const v8s*>(km + qkb + (long)kr0 * 512 + 32 + lg * 8);
#pragma unroll
    for (int f = 0; f < 13; f++) {
      v8s nb0 = b0, nb1 = b1;
      if (f < 12) {
        int kr = wk * 208 + (f + 1) * 16 + lr;
        if (kr > 399) kr = 399;
        nb0 = *reinterpret_cast<const v8s*>(km + qkb + (long)kr * 512 + lg * 8);
        nb1 = *reinterpret_cast<const v8s*>(km + qkb + (long)kr * 512 + 32 + lg * 8);
      }
      __builtin_amdgcn_s_setprio(1);
      acc[f] = mfma16(aq0, b0, acc[f]);
      acc[f] = mfma16(aq1, b1, acc[f]);
      __builtin_amdgcn_s_setprio(0);
      b0 = nb0;
      b1 = nb1;
    }
  }

  const long sb = ((long)h * 192 + bs) * 160000;
  const int rowb = q0 + wq * 16 + lg * 4;
  const int rloc = wq * 16 + lg * 4;
  float mx[4] = {-3.0e38f, -3.0e38f, -3.0e38f, -3.0e38f};
#pragma unroll
  for (int f = 0; f < 13; f++) {
    const int col = wk * 208 + f * 16 + lr;
#pragma unroll
    for (int r = 0; r < 4; r++) {
      float s = acc[f][r] * 0.125f;
      if (col >= 400) s = -3.0e38f;
      acc[f][r] = s;
      mx[r] = fmaxf(mx[r], s);
      if (col < 400 && rowb + r < 400)
        sc[sb + (long)(rowb + r) * 400 + col] = s;
    }
  }
#pragma unroll
  for (int d = 1; d < 16; d <<= 1)
#pragma unroll
    for (int r = 0; r < 4; r++) mx[r] = fmaxf(mx[r], __shfl_xor(mx[r], d));
  if (lr == 0) {
#pragma unroll
    for (int r = 0; r < 4; r++) redM[wk][rloc + r] = mx[r];
  }
  __syncthreads();

  float M[4], sum[4] = {0.f, 0.f, 0.f, 0.f};
#pragma unroll
  for (int r = 0; r < 4; r++) M[r] = fmaxf(redM[0][rloc + r], redM[1][rloc + r]);
#pragma unroll
  for (int f = 0; f < 13; f++) {
#pragma unroll
    for (int r = 0; r < 4; r++) {
      float p = __expf(acc[f][r] - M[r]);
      sum[r] += p;
      sP[rloc + r][wk * 208 + f * 16 + lr] = f2bf(p);
    }
  }
#pragma unroll
  for (int d = 1; d < 16; d <<= 1)
#pragma unroll
    for (int r = 0; r < 4; r++) sum[r] += __shfl_xor(sum[r], d);
  if (lr == 0) {
#pragma unroll
    for (int r = 0; r < 4; r++) redS[wk][rloc + r] = sum[r];
  }
  __syncthreads();

  float inv[4];
#pragma unroll
  for (int r = 0; r < 4; r++) inv[r] = 1.0f / (redS[0][rloc + r] + redS[1][rloc + r]);

  // PV: 2-deep pipeline (sP ds_read + 2 global V loads ahead), setprio on MFMA
  const long vtb = (long)g * 25600;
  const unsigned short* vrow0 = vt + vtb + (long)(wk * 32 + lr) * 400;
  const unsigned short* vrow1 = vt + vtb + (long)(wk * 32 + 16 + lr) * 400;
  f32x4 o0 = {0.f, 0.f, 0.f, 0.f}, o1 = {0.f, 0.f, 0.f, 0.f};
  {
    v8s pa = *reinterpret_cast<const v8s*>(&sP[wq * 16 + lr][lg * 8]);
    v8s bv0 = *reinterpret_cast<const v8s*>(vrow0 + lg * 8);
    v8s bv1 = *reinterpret_cast<const v8s*>(vrow1 + lg * 8);
#pragma unroll
    for (int ks = 0; ks < 13; ks++) {
      v8s npa = pa, nbv0 = bv0, nbv1 = bv1;
      if (ks < 12) {
        npa = *reinterpret_cast<const v8s*>(&sP[wq * 16 + lr][(ks + 1) * 32 + lg * 8]);
        nbv0 = *reinterpret_cast<const v8s*>(vrow0 + (ks + 1) * 32 + lg * 8);
        nbv1 = *reinterpret_cast<const v8s*>(vrow1 + (ks + 1) * 32 + lg * 8);
      }
      __builtin_amdgcn_s_setprio(1);
      o0 = mfma16(pa, bv0, o0);
      o1 = mfma16(pa, bv1, o1);
      __builtin_amdgcn_s_setprio(0);
      pa = npa;
      bv0 = nbv0;
      bv1 = nbv1;
    }
  }

  const long cb = (long)bs * 400 * 512 + h * 64 + wk * 32;
#pragma unroll
  for (int r = 0; r < 4; r++) {
    const int row = rowb + r;
    if (row < 400) {
      ctx[cb + (long)row * 512 + lr] = f2bf(o0[r] * inv[r]);
      ctx[cb + (long)row * 512 + 16 + lr] = f2bf(o1[r] * inv[r]);
    }
  }
}

// ---------------------------------------------------------------------------

extern "C" void kernel_launch(void* const* d_in, const int* in_sizes, int n_in,
                              void* d_out, int out_size, void* d_ws, size_t ws_size,
                              hipStream_t stream) {
  (void)in_sizes; (void)n_in; (void)out_size;

  const float* query = (const float*)d_in[0];
  const float* key   = (const float*)d_in[1];
  const float* value = (const float*)d_in[2];
  const float* Wq = (const float*)d_in[3];
  const float* bq = (const float*)d_in[4];
  const float* Wk = (const float*)d_in[5];
  const float* bk = (const float*)d_in[6];
  const float* Wv = (const float*)d_in[7];
  const float* bv = (const float*)d_in[8];
  const float* Wo = (const float*)d_in[9];
  const float* bo = (const float*)d_in[10];

  float* out = (float*)d_out;       // 39,321,600 f32
  float* sc  = out + 39321600ULL;   // 245,760,000 f32 (scores)
  float* vhb = sc + 245760000ULL;   // 39,321,600 f32

  char* ws = (char*)d_ws;
  unsigned short* wq_  = (unsigned short*)ws;                   // 78.6 MB
  unsigned short* wk_  = (unsigned short*)(ws + 78643200ULL);   // 78.6 MB
  unsigned short* wvt  = (unsigned short*)(ws + 157286400ULL);  // 78.6 MB
  unsigned short* wW   = (unsigned short*)(ws + 235929600ULL);  // 2 MB
  // ctx: prefer a dedicated region (no alias, no race surface). Fall back to
  // the r13 wq_-alias only if the workspace is too small. ws_size is constant
  // for the run, so the choice is deterministic across calls.
  unsigned short* wctx = (ws_size >= 316669952ULL)
                             ? (unsigned short*)(ws + 238026752ULL)
                             : wq_;

  dim3 blk(256);

  hipLaunchKernelGGL(cvtw_k, dim3(128, 4), blk, 0, stream, Wq, Wk, Wv, Wo, wW);

  hipLaunchKernelGGL(proj_k, dim3(7200), blk, 0, stream, query, key, value, wW,
                     bq, bk, bv, wq_, wk_, vhb, wvt);

  hipLaunchKernelGGL(attn_k, dim3(19968), blk, 0, stream, wq_, wk_, wvt, sc, wctx);

  hipLaunchKernelGGL(outgemm_k, dim3(2400), blk, 0, stream, wctx, wW + 786432,
                     bo, out);
}

// Round 16
// 915.602 us; speedup vs baseline: 1.5897x; 1.1210x over previous
//
#include <hip/hip_runtime.h>

// ---------------------------------------------------------------------------
// AttentionLayer: B=16 S=12 N=400 D=512 H=8 HD=64
// outputs (flat, fp32): out[16,12,400,512] | scores_hb[128,12,400,400]
//                       | v_hb[128,12,400,64]
// NOTE (r3, r9): __builtin_nontemporal_store on these fragment epilogues is a
// ~2x write-cost regression (64B segments, L2 write-merge is load-bearing).
// NOTE (r8): HW v_cvt_pk_bf16_f32 is not RNE — absmax 7.9e-2 fail. Use f2bf.
// NOTE (r11): GEMM K-loops 2-phase double-buffered (one barrier/k-step).
// NOTE (r12 diagnostic): proj ~300us, outgemm ~95us, attn ~650us, cvtw ~10us.
// NOTE (r13): proj A-pitch 40 / C-pitch 140 (bank floor); setprio on MFMA.
// NOTE (r14): attn sc-store/QK^T fusion caused replay-only divergence; keep
// phases separated. ctx de-aliased from wq_ when ws_size permits (r15).
// NOTE (r16): attn K/V panels LDS-staged (m97 pattern). Old per-fragment
// global gathers were 16 x 64B L2 segments per b128 load (rows at 1KB/800B
// stride). K staged once via gload16 with XOR-swizzled per-lane SOURCE
// (#21: linear dest + same XOR on ds_read: c16 ^= kr&7 -> bank floor);
// V staged flat into the SAME buffer during exp (K dead; barrier-separated;
// T14 overlap). LDS 78.9KB -> 2 blocks/CU.
// ---------------------------------------------------------------------------

typedef float fvec4 __attribute__((ext_vector_type(4)));
typedef float f32x4 __attribute__((ext_vector_type(4)));
typedef unsigned short usvec4 __attribute__((ext_vector_type(4)));
typedef unsigned short usvec8 __attribute__((ext_vector_type(8)));
typedef short v8s __attribute__((ext_vector_type(8)));

#define DEV __device__ __forceinline__

DEV unsigned short f2bf(float f) {
  unsigned int u = __builtin_bit_cast(unsigned int, f);
  u += 0x7FFFu + ((u >> 16) & 1u);  // RNE
  return (unsigned short)(u >> 16);
}

DEV f32x4 mfma16(v8s a, v8s b, f32x4 c) {
  return __builtin_amdgcn_mfma_f32_16x16x32_bf16(a, b, c, 0, 0, 0);
}

DEV void gload16(const void* g, void* l) {
  __builtin_amdgcn_global_load_lds(
      (const __attribute__((address_space(1))) unsigned int*)g,
      (__attribute__((address_space(3))) unsigned int*)l, 16, 0, 0);
}

// all 4 weight matrices (512x512 each) in one launch; blockIdx.y selects
__global__ __launch_bounds__(256) void cvtw_k(const float* __restrict__ w0,
                                              const float* __restrict__ w1,
                                              const float* __restrict__ w2,
                                              const float* __restrict__ w3,
                                              unsigned short* __restrict__ o) {
  const float* w = (blockIdx.y == 0) ? w0 : (blockIdx.y == 1) ? w1
                 : (blockIdx.y == 2) ? w2 : w3;
  unsigned short* op = o + (long)blockIdx.y * 262144;
  long i = ((long)blockIdx.x * 256 + threadIdx.x) * 8;  // grid.x=128 -> exact
  fvec4 a = *reinterpret_cast<const fvec4*>(w + i);
  fvec4 b = *reinterpret_cast<const fvec4*>(w + i + 4);
  usvec8 r;
  r[0] = f2bf(a[0]); r[1] = f2bf(a[1]); r[2] = f2bf(a[2]); r[3] = f2bf(a[3]);
  r[4] = f2bf(b[0]); r[5] = f2bf(b[1]); r[6] = f2bf(b[2]); r[7] = f2bf(b[3]);
  *reinterpret_cast<usvec8*>(op + i) = r;
}

// ---------------------------------------------------------------------------
// Merged projection GEMM (q,k,v in ONE launch; grid 7200 = 8*900 XCD-chunked).
// 2-phase dbuf; A fp32 reg-staged cvt (pitch 40 = bank floor); B gload16
// (linear pitch 32). C-tile epilogue pitch 140 (bank floor).
// ---------------------------------------------------------------------------
__global__ __launch_bounds__(256) void proj_k(
    const float* __restrict__ qin, const float* __restrict__ kin,
    const float* __restrict__ vin, const unsigned short* __restrict__ wW,
    const float* __restrict__ bqp, const float* __restrict__ bkp,
    const float* __restrict__ bvp, unsigned short* __restrict__ wq_,
    unsigned short* __restrict__ wk_, float* __restrict__ vhb,
    unsigned short* __restrict__ wvt) {
  __shared__ unsigned short sMem[18432];
  const int t = threadIdx.x;
  const int lane = t & 63, wid = t >> 6;
  const int wm = wid >> 1, wn = wid & 1;
  const int lr = lane & 15, lg = lane >> 4;
  const int bid = blockIdx.x;
  const int orig = (bid & 7) * 900 + (bid >> 3);
  const int which = orig >= 4800 ? 2 : (orig >= 2400 ? 1 : 0);
  const int inner = orig - which * 2400;
  const long m0 = (long)(inner >> 2) * 128;
  const int n0 = (inner & 3) * 128;

  const float* A = which == 0 ? qin : which == 1 ? kin : vin;
  const unsigned short* W = wW + (long)which * 262144;
  const float* bias = which == 0 ? bqp : which == 1 ? bkp : bvp;

  const int srow = wid * 16 + (lane >> 2);
  const int scol = (lane & 3) * 8;
  const unsigned short* bS0 = W + (long)(n0 + srow) * 512 + scol;
  const unsigned short* bS1 = bS0 + 64 * 512;
  const int bOff0 = wid * 512;
  const int bOff1 = (wid + 4) * 512;

  const int arow = t >> 3;       // 0..31
  const int acol = (t & 7) * 4;  // f32 col within k-tile
  const float* aP32 = A + (m0 + arow) * 512 + acol;
  const int aOff = arow * 40 + acol;  // pitch 40 shorts (80B) = bank floor

  f32x4 acc[4][4] = {};
  fvec4 aReg[4];
#pragma unroll
  for (int i = 0; i < 4; i++)
    aReg[i] = *reinterpret_cast<const fvec4*>(aP32 + (long)i * 16384);

  {  // prologue: stage tile 0 into buf0, prefetch A regs for tile 1
    unsigned short* sA0 = sMem;
    unsigned short* sB0 = sMem + 10240;
    gload16(bS0, sB0 + bOff0);
    gload16(bS1, sB0 + bOff1);
#pragma unroll
    for (int i = 0; i < 4; i++) {
      usvec4 pk;
      pk[0] = f2bf(aReg[i][0]); pk[1] = f2bf(aReg[i][1]);
      pk[2] = f2bf(aReg[i][2]); pk[3] = f2bf(aReg[i][3]);
      *reinterpret_cast<usvec4*>(sA0 + aOff + i * 1280) = pk;  // 32 rows * 40
    }
#pragma unroll
    for (int i = 0; i < 4; i++)
      aReg[i] = *reinterpret_cast<const fvec4*>(aP32 + (long)i * 16384 + 32);
  }
  __syncthreads();

  for (int k0 = 0; k0 < 512; k0 += 32) {
    const int c = (k0 >> 5) & 1;
    unsigned short* sAc = sMem + c * 5120;
    unsigned short* sBc = sMem + 10240 + c * 4096;
    if (k0 < 480) {  // stage tile k0+32 into buf^1
      unsigned short* sAn = sMem + (c ^ 1) * 5120;
      unsigned short* sBn = sMem + 10240 + (c ^ 1) * 4096;
      gload16(bS0 + k0 + 32, sBn + bOff0);
      gload16(bS1 + k0 + 32, sBn + bOff1);
#pragma unroll
      for (int i = 0; i < 4; i++) {
        usvec4 pk;
        pk[0] = f2bf(aReg[i][0]); pk[1] = f2bf(aReg[i][1]);
        pk[2] = f2bf(aReg[i][2]); pk[3] = f2bf(aReg[i][3]);
        *reinterpret_cast<usvec4*>(sAn + aOff + i * 1280) = pk;
      }
      if (k0 < 448) {
#pragma unroll
        for (int i = 0; i < 4; i++)
          aReg[i] = *reinterpret_cast<const fvec4*>(aP32 + (long)i * 16384 +
                                                    k0 + 64);
      }
    }

    v8s af[4], bf[4];
#pragma unroll
    for (int i = 0; i < 4; i++)
      af[i] = *reinterpret_cast<const v8s*>(&sAc[(wm * 64 + i * 16 + lr) * 40 + lg * 8]);
#pragma unroll
    for (int j = 0; j < 4; j++)
      bf[j] = *reinterpret_cast<const v8s*>(&sBc[(wn * 64 + j * 16 + lr) * 32 + lg * 8]);
    __builtin_amdgcn_s_setprio(1);
#pragma unroll
    for (int i = 0; i < 4; i++)
#pragma unroll
      for (int j = 0; j < 4; j++) acc[i][j] = mfma16(af[i], bf[j], acc[i][j]);
    __builtin_amdgcn_s_setprio(0);
    __syncthreads();
  }

  if (which <= 1) {
    unsigned short* o_h = which == 0 ? wq_ : wk_;
    // stage C tile (bf16, +bias) in LDS (pitch 140), coalesced 64B stores
#pragma unroll
    for (int i = 0; i < 4; i++) {
#pragma unroll
      for (int j = 0; j < 4; j++) {
        const int col = wn * 64 + j * 16 + lr;
        const float bv_ = bias[n0 + col];
#pragma unroll
        for (int r = 0; r < 4; r++) {
          const int row = wm * 64 + i * 16 + lg * 4 + r;
          sMem[row * 140 + col] = f2bf(acc[i][j][r] + bv_);
        }
      }
    }
    __syncthreads();
#pragma unroll
    for (int pass = 0; pass < 2; pass++) {
      const int row = (t >> 2) + pass * 64;
      const int c0 = (t & 3) * 8;
      const unsigned short* src = &sMem[row * 140 + c0];
      unsigned short* dst = &o_h[(m0 + row) * 512 + n0 + c0];
#pragma unroll
      for (int k = 0; k < 4; k++)
        *reinterpret_cast<usvec8*>(dst + k * 32) =
            *reinterpret_cast<const usvec8*>(src + k * 32);
    }
  } else {
#pragma unroll
    for (int i = 0; i < 4; i++) {
#pragma unroll
      for (int j = 0; j < 4; j++) {
        const int gn = n0 + wn * 64 + j * 16 + lr;
        const float bv_ = bias[gn];
        const long gm0 = m0 + wm * 64 + i * 16 + lg * 4;
        const int bs_lin = (int)(gm0 / 400);
        const int node0 = (int)(gm0 - (long)bs_lin * 400);
        const int h = gn >> 6, hd = gn & 63;
        float* vp = vhb + ((((long)(h * 192 + bs_lin) * 400 + node0) << 6) + hd);
        const float v0 = acc[i][j][0] + bv_, v1 = acc[i][j][1] + bv_;
        const float v2 = acc[i][j][2] + bv_, v3 = acc[i][j][3] + bv_;
        vp[0] = v0;
        vp[64] = v1;
        vp[128] = v2;
        vp[192] = v3;
        usvec4 pk;
        pk[0] = f2bf(v0); pk[1] = f2bf(v1); pk[2] = f2bf(v2); pk[3] = f2bf(v3);
        *reinterpret_cast<usvec4*>(
            wvt + (((long)(bs_lin * 8 + h) * 64 + hd) * 400 + node0)) = pk;
      }
    }
  }
}

// ---------------------------------------------------------------------------
// Output GEMM: 2-phase dbuf, gload16 A and B (linear 32-pitch = read floor).
// ---------------------------------------------------------------------------
__global__ __launch_bounds__(256) void outgemm_k(
    const unsigned short* __restrict__ A, const unsigned short* __restrict__ W,
    const float* __restrict__ bias, float* __restrict__ o_f) {
  __shared__ unsigned short sMem[16384];
  const int t = threadIdx.x;
  const int lane = t & 63, wid = t >> 6;
  const int wm = wid >> 1, wn = wid & 1;
  const int lr = lane & 15, lg = lane >> 4;
  const int bid = blockIdx.x;
  const int orig = (bid & 7) * 300 + (bid >> 3);
  const long m0 = (long)(orig >> 2) * 128;
  const int n0 = (orig & 3) * 128;

  const int srow = wid * 16 + (lane >> 2);
  const int scol = (lane & 3) * 8;
  const unsigned short* aS0 = A + (m0 + srow) * 512 + scol;
  const unsigned short* aS1 = aS0 + 64 * 512;
  const unsigned short* bS0 = W + (long)(n0 + srow) * 512 + scol;
  const unsigned short* bS1 = bS0 + 64 * 512;
  const int bOff0 = wid * 512;
  const int bOff1 = (wid + 4) * 512;

  f32x4 acc[4][4] = {};

  {
    gload16(aS0, sMem + bOff0);
    gload16(aS1, sMem + bOff1);
    gload16(bS0, sMem + 8192 + bOff0);
    gload16(bS1, sMem + 8192 + bOff1);
  }
  __syncthreads();

  for (int k0 = 0; k0 < 512; k0 += 32) {
    const int c = (k0 >> 5) & 1;
    unsigned short* sAc = sMem + c * 4096;
    unsigned short* sBc = sMem + 8192 + c * 4096;
    if (k0 < 480) {
      unsigned short* sAn = sMem + (c ^ 1) * 4096;
      unsigned short* sBn = sMem + 8192 + (c ^ 1) * 4096;
      gload16(aS0 + k0 + 32, sAn + bOff0);
      gload16(aS1 + k0 + 32, sAn + bOff1);
      gload16(bS0 + k0 + 32, sBn + bOff0);
      gload16(bS1 + k0 + 32, sBn + bOff1);
    }

    v8s af[4], bf[4];
#pragma unroll
    for (int i = 0; i < 4; i++)
      af[i] = *reinterpret_cast<const v8s*>(&sAc[(wm * 64 + i * 16 + lr) * 32 + lg * 8]);
#pragma unroll
    for (int j = 0; j < 4; j++)
      bf[j] = *reinterpret_cast<const v8s*>(&sBc[(wn * 64 + j * 16 + lr) * 32 + lg * 8]);
    __builtin_amdgcn_s_setprio(1);
#pragma unroll
    for (int i = 0; i < 4; i++)
#pragma unroll
      for (int j = 0; j < 4; j++) acc[i][j] = mfma16(af[i], bf[j], acc[i][j]);
    __builtin_amdgcn_s_setprio(0);
    __syncthreads();
  }

#pragma unroll
  for (int i = 0; i < 4; i++) {
#pragma unroll
    for (int j = 0; j < 4; j++) {
      const int gn = n0 + wn * 64 + j * 16 + lr;
      const float bv_ = bias[gn];
#pragma unroll
      for (int r = 0; r < 4; r++) {
        const long gm = m0 + wm * 64 + i * 16 + lg * 4 + r;
        o_f[gm * 512 + gn] = acc[i][j][r] + bv_;
      }
    }
  }
}

// ---------------------------------------------------------------------------
// Fused attention (r16): K/V panels LDS-staged.
//  - K (400x64, 51.2KB): gload16 at block start, XOR-swizzled per-lane source
//    (content(row,c16) = K[row][(c16^(row&7))*8]); QK^T B-frags = ds_read_b128
//    at kr*64 + ((c^(kr&7))*8 -> 2/bank floor.
//  - V (64x400, flat): gload16 into the SAME buffer right after barrier 1
//    (K dead); latency hides under exp (T14); barrier 2's vmcnt-drain covers.
// LDS: 51264 + 27136 + 512 = 78912B -> 2 blocks/CU.
// 1D grid 19968 (= 8*2496), XCD-chunked swizzle, qb fastest (K/V L2 reuse).
// ---------------------------------------------------------------------------
__global__ __launch_bounds__(256) void attn_k(
    const unsigned short* __restrict__ qm, const unsigned short* __restrict__ km,
    const unsigned short* __restrict__ vt, float* __restrict__ sc,
    unsigned short* __restrict__ ctx) {
  __shared__ __align__(16) unsigned short sKV[25632];
  __shared__ __align__(16) unsigned short sP[32][424];
  __shared__ float redM[2][32], redS[2][32];
  const int t = threadIdx.x;
  const int lane = t & 63, wid = t >> 6;
  const int wq = wid >> 1, wk = wid & 1;
  const int lr = lane & 15, lg = lane >> 4;
  const int bid = blockIdx.x;
  const int orig = (bid & 7) * 2496 + (bid >> 3);
  const int g = orig / 13, qb = orig - g * 13;
  const int bs = g >> 3, h = g & 7;
  const int q0 = qb * 32;
  const long qkb = (long)bs * 204800 + h * 64;
  const long vtb = (long)g * 25600;

  // --- Stage K panel (rows i*8+(lane>>3), c16 = lane&7; row&7 == lane>>3) ---
  {
    const unsigned short* kbase = km + qkb + (((lane & 7) ^ (lane >> 3)) << 3);
    for (int i = wid; i < 50; i += 4)
      gload16(kbase + (long)(i * 8 + (lane >> 3)) * 512, sKV + i * 512);
  }

  int qrow = q0 + wq * 16 + lr;
  if (qrow > 399) qrow = 399;
  const v8s aq0 = *reinterpret_cast<const v8s*>(qm + qkb + (long)qrow * 512 + lg * 8);
  const v8s aq1 = *reinterpret_cast<const v8s*>(qm + qkb + (long)qrow * 512 + 32 + lg * 8);

  __syncthreads();  // K staged (barrier drains vmcnt)

  f32x4 acc[13];
#pragma unroll
  for (int f = 0; f < 13; f++) acc[f] = f32x4{0.f, 0.f, 0.f, 0.f};

  // QK^T: B-frags from swizzled LDS K
#pragma unroll
  for (int f = 0; f < 13; f++) {
    int kr = wk * 208 + f * 16 + lr;
    if (kr > 399) kr = 399;
    const int sw = kr & 7;
    const v8s b0 = *reinterpret_cast<const v8s*>(sKV + kr * 64 + ((lg ^ sw) << 3));
    const v8s b1 = *reinterpret_cast<const v8s*>(sKV + kr * 64 + (((4 + lg) ^ sw) << 3));
    __builtin_amdgcn_s_setprio(1);
    acc[f] = mfma16(aq0, b0, acc[f]);
    acc[f] = mfma16(aq1, b1, acc[f]);
    __builtin_amdgcn_s_setprio(0);
  }

  const long sb = ((long)h * 192 + bs) * 160000;
  const int rowb = q0 + wq * 16 + lg * 4;
  const int rloc = wq * 16 + lg * 4;
  float mx[4] = {-3.0e38f, -3.0e38f, -3.0e38f, -3.0e38f};
#pragma unroll
  for (int f = 0; f < 13; f++) {
    const int col = wk * 208 + f * 16 + lr;
#pragma unroll
    for (int r = 0; r < 4; r++) {
      float s = acc[f][r] * 0.125f;
      if (col >= 400) s = -3.0e38f;
      acc[f][r] = s;
      mx[r] = fmaxf(mx[r], s);
      if (col < 400 && rowb + r < 400)
        sc[sb + (long)(rowb + r) * 400 + col] = s;
    }
  }
#pragma unroll
  for (int d = 1; d < 16; d <<= 1)
#pragma unroll
    for (int r = 0; r < 4; r++) mx[r] = fmaxf(mx[r], __shfl_xor(mx[r], d));
  if (lr == 0) {
#pragma unroll
    for (int r = 0; r < 4; r++) redM[wk][rloc + r] = mx[r];
  }
  __syncthreads();  // also: all K ds_reads done -> sKV reusable for V

  // --- Stage V panel (flat 51.2KB copy); latency hides under exp (T14) ---
  for (int i = wid; i < 50; i += 4)
    gload16(vt + vtb + i * 512 + lane * 8, sKV + i * 512);

  float M[4], sum[4] = {0.f, 0.f, 0.f, 0.f};
#pragma unroll
  for (int r = 0; r < 4; r++) M[r] = fmaxf(redM[0][rloc + r], redM[1][rloc + r]);
#pragma unroll
  for (int f = 0; f < 13; f++) {
#pragma unroll
    for (int r = 0; r < 4; r++) {
      float p = __expf(acc[f][r] - M[r]);
      sum[r] += p;
      sP[rloc + r][wk * 208 + f * 16 + lr] = f2bf(p);
    }
  }
#pragma unroll
  for (int d = 1; d < 16; d <<= 1)
#pragma unroll
    for (int r = 0; r < 4; r++) sum[r] += __shfl_xor(sum[r], d);
  if (lr == 0) {
#pragma unroll
    for (int r = 0; r < 4; r++) redS[wk][rloc + r] = sum[r];
  }
  __syncthreads();  // sP visible + V gload16s drained (vmcnt)

  float inv[4];
#pragma unroll
  for (int r = 0; r < 4; r++) inv[r] = 1.0f / (redS[0][rloc + r] + redS[1][rloc + r]);

  // PV: A-frag from sP, B-frags from LDS V (flat [64][400]; ks=12 overreads
  // into next row are zero-multiplied by sP's pad-col zeros; buffer padded).
  const unsigned short* v0p = sKV + (wk * 32 + lr) * 400;
  const unsigned short* v1p = v0p + 6400;  // +16 rows
  f32x4 o0 = {0.f, 0.f, 0.f, 0.f}, o1 = {0.f, 0.f, 0.f, 0.f};
#pragma unroll
  for (int ks = 0; ks < 13; ks++) {
    const v8s pa = *reinterpret_cast<const v8s*>(&sP[wq * 16 + lr][ks * 32 + lg * 8]);
    const v8s bv0 = *reinterpret_cast<const v8s*>(v0p + ks * 32 + lg * 8);
    const v8s bv1 = *reinterpret_cast<const v8s*>(v1p + ks * 32 + lg * 8);
    __builtin_amdgcn_s_setprio(1);
    o0 = mfma16(pa, bv0, o0);
    o1 = mfma16(pa, bv1, o1);
    __builtin_amdgcn_s_setprio(0);
  }

  const long cb = (long)bs * 400 * 512 + h * 64 + wk * 32;
#pragma unroll
  for (int r = 0; r < 4; r++) {
    const int row = rowb + r;
    if (row < 400) {
      ctx[cb + (long)row * 512 + lr] = f2bf(o0[r] * inv[r]);
      ctx[cb + (long)row * 512 + 16 + lr] = f2bf(o1[r] * inv[r]);
    }
  }
}

// ---------------------------------------------------------------------------

extern "C" void kernel_launch(void* const* d_in, const int* in_sizes, int n_in,
                              void* d_out, int out_size, void* d_ws, size_t ws_size,
                              hipStream_t stream) {
  (void)in_sizes; (void)n_in; (void)out_size;

  const float* query = (const float*)d_in[0];
  const float* key   = (const float*)d_in[1];
  const float* value = (const float*)d_in[2];
  const float* Wq = (const float*)d_in[3];
  const float* bq = (const float*)d_in[4];
  const float* Wk = (const float*)d_in[5];
  const float* bk = (const float*)d_in[6];
  const float* Wv = (const float*)d_in[7];
  const float* bv = (const float*)d_in[8];
  const float* Wo = (const float*)d_in[9];
  const float* bo = (const float*)d_in[10];

  float* out = (float*)d_out;       // 39,321,600 f32
  float* sc  = out + 39321600ULL;   // 245,760,000 f32 (scores)
  float* vhb = sc + 245760000ULL;   // 39,321,600 f32

  char* ws = (char*)d_ws;
  unsigned short* wq_  = (unsigned short*)ws;                   // 78.6 MB
  unsigned short* wk_  = (unsigned short*)(ws + 78643200ULL);   // 78.6 MB
  unsigned short* wvt  = (unsigned short*)(ws + 157286400ULL);  // 78.6 MB
  unsigned short* wW   = (unsigned short*)(ws + 235929600ULL);  // 2 MB
  // ctx: dedicated region when workspace permits (no alias, no race surface).
  unsigned short* wctx = (ws_size >= 316669952ULL)
                             ? (unsigned short*)(ws + 238026752ULL)
                             : wq_;

  dim3 blk(256);

  hipLaunchKernelGGL(cvtw_k, dim3(128, 4), blk, 0, stream, Wq, Wk, Wv, Wo, wW);

  hipLaunchKernelGGL(proj_k, dim3(7200), blk, 0, stream, query, key, value, wW,
                     bq, bk, bv, wq_, wk_, vhb, wvt);

  hipLaunchKernelGGL(attn_k, dim3(19968), blk, 0, stream, wq_, wk_, wvt, sc, wctx);

  hipLaunchKernelGGL(outgemm_k, dim3(2400), blk, 0, stream, wctx, wW + 786432,
                     bo, out);
}

// Round 17
// 797.142 us; speedup vs baseline: 1.8260x; 1.1486x over previous
//
#include <hip/hip_runtime.h>

// ---------------------------------------------------------------------------
// AttentionLayer: B=16 S=12 N=400 D=512 H=8 HD=64
// outputs (flat, fp32): out[16,12,400,512] | scores_hb[128,12,400,400]
//                       | v_hb[128,12,400,64]
// NOTE (r3, r9): __builtin_nontemporal_store on these fragment epilogues is a
// ~2x write-cost regression (64B segments, L2 write-merge is load-bearing).
// NOTE (r8): HW v_cvt_pk_bf16_f32 is not RNE — absmax 7.9e-2 fail. Use f2bf.
// NOTE (r11): GEMM K-loops 2-phase double-buffered (one barrier/k-step).
// NOTE (r12 diagnostic): proj ~300us, outgemm ~95us, attn ~650us, cvtw ~10us.
// NOTE (r13): proj A-pitch 40 / C-pitch 140 (bank floor); setprio on MFMA.
// NOTE (r14): attn sc-store/QK^T fusion caused replay-only divergence; keep
// phases separated. ctx de-aliased from wq_ when ws_size permits (r15).
// NOTE (r16): attn K/V LDS-staged (K XOR-swizzled source, rule #21). 916us.
// NOTE (r17): attn re-staged K/V 13x per group (19968 blocks). Now ONE block
// per group (grid 1536, 512 thr, 8 waves): K+V staged once into separate
// buffers (sK 51.2K + sV 51.3K + sP 54.3K + red 1K = 157.8KB, 1 block/CU),
// loop over 7 q-tiles of 64 rows. Staging traffic/latency /13. Per-wave
// fragment geometry identical to r16 (verified); barrier pair per q-tile
// orders sP/redM/redS reuse (PV lgkm drains at next tile's barrier 1).
// ---------------------------------------------------------------------------

typedef float fvec4 __attribute__((ext_vector_type(4)));
typedef float f32x4 __attribute__((ext_vector_type(4)));
typedef unsigned short usvec4 __attribute__((ext_vector_type(4)));
typedef unsigned short usvec8 __attribute__((ext_vector_type(8)));
typedef short v8s __attribute__((ext_vector_type(8)));

#define DEV __device__ __forceinline__

DEV unsigned short f2bf(float f) {
  unsigned int u = __builtin_bit_cast(unsigned int, f);
  u += 0x7FFFu + ((u >> 16) & 1u);  // RNE
  return (unsigned short)(u >> 16);
}

DEV f32x4 mfma16(v8s a, v8s b, f32x4 c) {
  return __builtin_amdgcn_mfma_f32_16x16x32_bf16(a, b, c, 0, 0, 0);
}

DEV void gload16(const void* g, void* l) {
  __builtin_amdgcn_global_load_lds(
      (const __attribute__((address_space(1))) unsigned int*)g,
      (__attribute__((address_space(3))) unsigned int*)l, 16, 0, 0);
}

// all 4 weight matrices (512x512 each) in one launch; blockIdx.y selects
__global__ __launch_bounds__(256) void cvtw_k(const float* __restrict__ w0,
                                              const float* __restrict__ w1,
                                              const float* __restrict__ w2,
                                              const float* __restrict__ w3,
                                              unsigned short* __restrict__ o) {
  const float* w = (blockIdx.y == 0) ? w0 : (blockIdx.y == 1) ? w1
                 : (blockIdx.y == 2) ? w2 : w3;
  unsigned short* op = o + (long)blockIdx.y * 262144;
  long i = ((long)blockIdx.x * 256 + threadIdx.x) * 8;  // grid.x=128 -> exact
  fvec4 a = *reinterpret_cast<const fvec4*>(w + i);
  fvec4 b = *reinterpret_cast<const fvec4*>(w + i + 4);
  usvec8 r;
  r[0] = f2bf(a[0]); r[1] = f2bf(a[1]); r[2] = f2bf(a[2]); r[3] = f2bf(a[3]);
  r[4] = f2bf(b[0]); r[5] = f2bf(b[1]); r[6] = f2bf(b[2]); r[7] = f2bf(b[3]);
  *reinterpret_cast<usvec8*>(op + i) = r;
}

// ---------------------------------------------------------------------------
// Merged projection GEMM (q,k,v in ONE launch; grid 7200 = 8*900 XCD-chunked).
// 2-phase dbuf; A fp32 reg-staged cvt (pitch 40 = bank floor); B gload16
// (linear pitch 32). C-tile epilogue pitch 140 (bank floor).
// ---------------------------------------------------------------------------
__global__ __launch_bounds__(256) void proj_k(
    const float* __restrict__ qin, const float* __restrict__ kin,
    const float* __restrict__ vin, const unsigned short* __restrict__ wW,
    const float* __restrict__ bqp, const float* __restrict__ bkp,
    const float* __restrict__ bvp, unsigned short* __restrict__ wq_,
    unsigned short* __restrict__ wk_, float* __restrict__ vhb,
    unsigned short* __restrict__ wvt) {
  __shared__ unsigned short sMem[18432];
  const int t = threadIdx.x;
  const int lane = t & 63, wid = t >> 6;
  const int wm = wid >> 1, wn = wid & 1;
  const int lr = lane & 15, lg = lane >> 4;
  const int bid = blockIdx.x;
  const int orig = (bid & 7) * 900 + (bid >> 3);
  const int which = orig >= 4800 ? 2 : (orig >= 2400 ? 1 : 0);
  const int inner = orig - which * 2400;
  const long m0 = (long)(inner >> 2) * 128;
  const int n0 = (inner & 3) * 128;

  const float* A = which == 0 ? qin : which == 1 ? kin : vin;
  const unsigned short* W = wW + (long)which * 262144;
  const float* bias = which == 0 ? bqp : which == 1 ? bkp : bvp;

  const int srow = wid * 16 + (lane >> 2);
  const int scol = (lane & 3) * 8;
  const unsigned short* bS0 = W + (long)(n0 + srow) * 512 + scol;
  const unsigned short* bS1 = bS0 + 64 * 512;
  const int bOff0 = wid * 512;
  const int bOff1 = (wid + 4) * 512;

  const int arow = t >> 3;       // 0..31
  const int acol = (t & 7) * 4;  // f32 col within k-tile
  const float* aP32 = A + (m0 + arow) * 512 + acol;
  const int aOff = arow * 40 + acol;  // pitch 40 shorts (80B) = bank floor

  f32x4 acc[4][4] = {};
  fvec4 aReg[4];
#pragma unroll
  for (int i = 0; i < 4; i++)
    aReg[i] = *reinterpret_cast<const fvec4*>(aP32 + (long)i * 16384);

  {  // prologue: stage tile 0 into buf0, prefetch A regs for tile 1
    unsigned short* sA0 = sMem;
    unsigned short* sB0 = sMem + 10240;
    gload16(bS0, sB0 + bOff0);
    gload16(bS1, sB0 + bOff1);
#pragma unroll
    for (int i = 0; i < 4; i++) {
      usvec4 pk;
      pk[0] = f2bf(aReg[i][0]); pk[1] = f2bf(aReg[i][1]);
      pk[2] = f2bf(aReg[i][2]); pk[3] = f2bf(aReg[i][3]);
      *reinterpret_cast<usvec4*>(sA0 + aOff + i * 1280) = pk;  // 32 rows * 40
    }
#pragma unroll
    for (int i = 0; i < 4; i++)
      aReg[i] = *reinterpret_cast<const fvec4*>(aP32 + (long)i * 16384 + 32);
  }
  __syncthreads();

  for (int k0 = 0; k0 < 512; k0 += 32) {
    const int c = (k0 >> 5) & 1;
    unsigned short* sAc = sMem + c * 5120;
    unsigned short* sBc = sMem + 10240 + c * 4096;
    if (k0 < 480) {  // stage tile k0+32 into buf^1
      unsigned short* sAn = sMem + (c ^ 1) * 5120;
      unsigned short* sBn = sMem + 10240 + (c ^ 1) * 4096;
      gload16(bS0 + k0 + 32, sBn + bOff0);
      gload16(bS1 + k0 + 32, sBn + bOff1);
#pragma unroll
      for (int i = 0; i < 4; i++) {
        usvec4 pk;
        pk[0] = f2bf(aReg[i][0]); pk[1] = f2bf(aReg[i][1]);
        pk[2] = f2bf(aReg[i][2]); pk[3] = f2bf(aReg[i][3]);
        *reinterpret_cast<usvec4*>(sAn + aOff + i * 1280) = pk;
      }
      if (k0 < 448) {
#pragma unroll
        for (int i = 0; i < 4; i++)
          aReg[i] = *reinterpret_cast<const fvec4*>(aP32 + (long)i * 16384 +
                                                    k0 + 64);
      }
    }

    v8s af[4], bf[4];
#pragma unroll
    for (int i = 0; i < 4; i++)
      af[i] = *reinterpret_cast<const v8s*>(&sAc[(wm * 64 + i * 16 + lr) * 40 + lg * 8]);
#pragma unroll
    for (int j = 0; j < 4; j++)
      bf[j] = *reinterpret_cast<const v8s*>(&sBc[(wn * 64 + j * 16 + lr) * 32 + lg * 8]);
    __builtin_amdgcn_s_setprio(1);
#pragma unroll
    for (int i = 0; i < 4; i++)
#pragma unroll
      for (int j = 0; j < 4; j++) acc[i][j] = mfma16(af[i], bf[j], acc[i][j]);
    __builtin_amdgcn_s_setprio(0);
    __syncthreads();
  }

  if (which <= 1) {
    unsigned short* o_h = which == 0 ? wq_ : wk_;
    // stage C tile (bf16, +bias) in LDS (pitch 140), coalesced 64B stores
#pragma unroll
    for (int i = 0; i < 4; i++) {
#pragma unroll
      for (int j = 0; j < 4; j++) {
        const int col = wn * 64 + j * 16 + lr;
        const float bv_ = bias[n0 + col];
#pragma unroll
        for (int r = 0; r < 4; r++) {
          const int row = wm * 64 + i * 16 + lg * 4 + r;
          sMem[row * 140 + col] = f2bf(acc[i][j][r] + bv_);
        }
      }
    }
    __syncthreads();
#pragma unroll
    for (int pass = 0; pass < 2; pass++) {
      const int row = (t >> 2) + pass * 64;
      const int c0 = (t & 3) * 8;
      const unsigned short* src = &sMem[row * 140 + c0];
      unsigned short* dst = &o_h[(m0 + row) * 512 + n0 + c0];
#pragma unroll
      for (int k = 0; k < 4; k++)
        *reinterpret_cast<usvec8*>(dst + k * 32) =
            *reinterpret_cast<const usvec8*>(src + k * 32);
    }
  } else {
#pragma unroll
    for (int i = 0; i < 4; i++) {
#pragma unroll
      for (int j = 0; j < 4; j++) {
        const int gn = n0 + wn * 64 + j * 16 + lr;
        const float bv_ = bias[gn];
        const long gm0 = m0 + wm * 64 + i * 16 + lg * 4;
        const int bs_lin = (int)(gm0 / 400);
        const int node0 = (int)(gm0 - (long)bs_lin * 400);
        const int h = gn >> 6, hd = gn & 63;
        float* vp = vhb + ((((long)(h * 192 + bs_lin) * 400 + node0) << 6) + hd);
        const float v0 = acc[i][j][0] + bv_, v1 = acc[i][j][1] + bv_;
        const float v2 = acc[i][j][2] + bv_, v3 = acc[i][j][3] + bv_;
        vp[0] = v0;
        vp[64] = v1;
        vp[128] = v2;
        vp[192] = v3;
        usvec4 pk;
        pk[0] = f2bf(v0); pk[1] = f2bf(v1); pk[2] = f2bf(v2); pk[3] = f2bf(v3);
        *reinterpret_cast<usvec4*>(
            wvt + (((long)(bs_lin * 8 + h) * 64 + hd) * 400 + node0)) = pk;
      }
    }
  }
}

// ---------------------------------------------------------------------------
// Output GEMM: 2-phase dbuf, gload16 A and B (linear 32-pitch = read floor).
// ---------------------------------------------------------------------------
__global__ __launch_bounds__(256) void outgemm_k(
    const unsigned short* __restrict__ A, const unsigned short* __restrict__ W,
    const float* __restrict__ bias, float* __restrict__ o_f) {
  __shared__ unsigned short sMem[16384];
  const int t = threadIdx.x;
  const int lane = t & 63, wid = t >> 6;
  const int wm = wid >> 1, wn = wid & 1;
  const int lr = lane & 15, lg = lane >> 4;
  const int bid = blockIdx.x;
  const int orig = (bid & 7) * 300 + (bid >> 3);
  const long m0 = (long)(orig >> 2) * 128;
  const int n0 = (orig & 3) * 128;

  const int srow = wid * 16 + (lane >> 2);
  const int scol = (lane & 3) * 8;
  const unsigned short* aS0 = A + (m0 + srow) * 512 + scol;
  const unsigned short* aS1 = aS0 + 64 * 512;
  const unsigned short* bS0 = W + (long)(n0 + srow) * 512 + scol;
  const unsigned short* bS1 = bS0 + 64 * 512;
  const int bOff0 = wid * 512;
  const int bOff1 = (wid + 4) * 512;

  f32x4 acc[4][4] = {};

  {
    gload16(aS0, sMem + bOff0);
    gload16(aS1, sMem + bOff1);
    gload16(bS0, sMem + 8192 + bOff0);
    gload16(bS1, sMem + 8192 + bOff1);
  }
  __syncthreads();

  for (int k0 = 0; k0 < 512; k0 += 32) {
    const int c = (k0 >> 5) & 1;
    unsigned short* sAc = sMem + c * 4096;
    unsigned short* sBc = sMem + 8192 + c * 4096;
    if (k0 < 480) {
      unsigned short* sAn = sMem + (c ^ 1) * 4096;
      unsigned short* sBn = sMem + 8192 + (c ^ 1) * 4096;
      gload16(aS0 + k0 + 32, sAn + bOff0);
      gload16(aS1 + k0 + 32, sAn + bOff1);
      gload16(bS0 + k0 + 32, sBn + bOff0);
      gload16(bS1 + k0 + 32, sBn + bOff1);
    }

    v8s af[4], bf[4];
#pragma unroll
    for (int i = 0; i < 4; i++)
      af[i] = *reinterpret_cast<const v8s*>(&sAc[(wm * 64 + i * 16 + lr) * 32 + lg * 8]);
#pragma unroll
    for (int j = 0; j < 4; j++)
      bf[j] = *reinterpret_cast<const v8s*>(&sBc[(wn * 64 + j * 16 + lr) * 32 + lg * 8]);
    __builtin_amdgcn_s_setprio(1);
#pragma unroll
    for (int i = 0; i < 4; i++)
#pragma unroll
      for (int j = 0; j < 4; j++) acc[i][j] = mfma16(af[i], bf[j], acc[i][j]);
    __builtin_amdgcn_s_setprio(0);
    __syncthreads();
  }

#pragma unroll
  for (int i = 0; i < 4; i++) {
#pragma unroll
    for (int j = 0; j < 4; j++) {
      const int gn = n0 + wn * 64 + j * 16 + lr;
      const float bv_ = bias[gn];
#pragma unroll
      for (int r = 0; r < 4; r++) {
        const long gm = m0 + wm * 64 + i * 16 + lg * 4 + r;
        o_f[gm * 512 + gn] = acc[i][j][r] + bv_;
      }
    }
  }
}

// ---------------------------------------------------------------------------
// Fused attention (r17): ONE block per (bs,h) group; 512 threads (8 waves:
// wq=wid>>1 in 0..3 -> 16 q-rows each, wk=wid&1 -> 208-col half). K and V
// staged ONCE (separate buffers), then loop over 7 q-tiles of 64 rows.
// Per-wave fragment geometry identical to r16 (verified).
// ---------------------------------------------------------------------------
__global__ __launch_bounds__(512) void attn_k(
    const unsigned short* __restrict__ qm, const unsigned short* __restrict__ km,
    const unsigned short* __restrict__ vt, float* __restrict__ sc,
    unsigned short* __restrict__ ctx) {
  __shared__ __align__(16) unsigned short sK[25600];   // [400][64] swizzled
  __shared__ __align__(16) unsigned short sV[25632];   // [64][400] flat (+pad)
  __shared__ __align__(16) unsigned short sP[64][424];
  __shared__ float redM[2][64], redS[2][64];
  const int t = threadIdx.x;
  const int lane = t & 63, wid = t >> 6;  // 8 waves
  const int wq = wid >> 1, wk = wid & 1;  // wq 0..3, wk 0..1
  const int lr = lane & 15, lg = lane >> 4;
  const int g = blockIdx.x;  // 1536 groups
  const int bs = g >> 3, h = g & 7;
  const long qkb = (long)bs * 204800 + h * 64;
  const long vtb = (long)g * 25600;

  // --- Stage K panel once (XOR-swizzled per-lane source; rule #21) ---
  {
    const unsigned short* kbase = km + qkb + (((lane & 7) ^ (lane >> 3)) << 3);
    for (int i = wid; i < 50; i += 8)
      gload16(kbase + (long)(i * 8 + (lane >> 3)) * 512, sK + i * 512);
  }
  // --- Stage V panel once (flat copy) ---
  for (int i = wid; i < 50; i += 8)
    gload16(vt + vtb + i * 512 + lane * 8, sV + i * 512);

  __syncthreads();  // staging drained

  const long sb = ((long)h * 192 + bs) * 160000;
  const unsigned short* v0p = sV + (wk * 32 + lr) * 400;
  const unsigned short* v1p = v0p + 6400;  // +16 hd-rows
  const long cb = (long)bs * 400 * 512 + h * 64 + wk * 32;

  for (int qt = 0; qt < 7; ++qt) {
    const int q0 = qt * 64;
    int qrow = q0 + wq * 16 + lr;
    if (qrow > 399) qrow = 399;
    const v8s aq0 =
        *reinterpret_cast<const v8s*>(qm + qkb + (long)qrow * 512 + lg * 8);
    const v8s aq1 =
        *reinterpret_cast<const v8s*>(qm + qkb + (long)qrow * 512 + 32 + lg * 8);

    f32x4 acc[13];
#pragma unroll
    for (int f = 0; f < 13; f++) acc[f] = f32x4{0.f, 0.f, 0.f, 0.f};

    // QK^T: B-frags from swizzled LDS K
#pragma unroll
    for (int f = 0; f < 13; f++) {
      int kr = wk * 208 + f * 16 + lr;
      if (kr > 399) kr = 399;
      const int sw = kr & 7;
      const v8s b0 = *reinterpret_cast<const v8s*>(sK + kr * 64 + ((lg ^ sw) << 3));
      const v8s b1 =
          *reinterpret_cast<const v8s*>(sK + kr * 64 + (((4 + lg) ^ sw) << 3));
      __builtin_amdgcn_s_setprio(1);
      acc[f] = mfma16(aq0, b0, acc[f]);
      acc[f] = mfma16(aq1, b1, acc[f]);
      __builtin_amdgcn_s_setprio(0);
    }

    const int rowb = q0 + wq * 16 + lg * 4;
    const int rloc = wq * 16 + lg * 4;
    float mx[4] = {-3.0e38f, -3.0e38f, -3.0e38f, -3.0e38f};
#pragma unroll
    for (int f = 0; f < 13; f++) {
      const int col = wk * 208 + f * 16 + lr;
#pragma unroll
      for (int r = 0; r < 4; r++) {
        float s = acc[f][r] * 0.125f;
        if (col >= 400) s = -3.0e38f;
        acc[f][r] = s;
        mx[r] = fmaxf(mx[r], s);
        if (col < 400 && rowb + r < 400)
          sc[sb + (long)(rowb + r) * 400 + col] = s;
      }
    }
#pragma unroll
    for (int d = 1; d < 16; d <<= 1)
#pragma unroll
      for (int r = 0; r < 4; r++) mx[r] = fmaxf(mx[r], __shfl_xor(mx[r], d));
    if (lr == 0) {
#pragma unroll
      for (int r = 0; r < 4; r++) redM[wk][rloc + r] = mx[r];
    }
    __syncthreads();  // barrier 1: redM visible; prev tile's sP reads done

    float M[4], sum[4] = {0.f, 0.f, 0.f, 0.f};
#pragma unroll
    for (int r = 0; r < 4; r++)
      M[r] = fmaxf(redM[0][rloc + r], redM[1][rloc + r]);
#pragma unroll
    for (int f = 0; f < 13; f++) {
#pragma unroll
      for (int r = 0; r < 4; r++) {
        float p = __expf(acc[f][r] - M[r]);
        sum[r] += p;
        sP[rloc + r][wk * 208 + f * 16 + lr] = f2bf(p);
      }
    }
#pragma unroll
    for (int d = 1; d < 16; d <<= 1)
#pragma unroll
      for (int r = 0; r < 4; r++) sum[r] += __shfl_xor(sum[r], d);
    if (lr == 0) {
#pragma unroll
      for (int r = 0; r < 4; r++) redS[wk][rloc + r] = sum[r];
    }
    __syncthreads();  // barrier 2: sP + redS visible

    float inv[4];
#pragma unroll
    for (int r = 0; r < 4; r++)
      inv[r] = 1.0f / (redS[0][rloc + r] + redS[1][rloc + r]);

    // PV: A-frag from sP, B-frags from LDS V ([64][400]; k>=400 elements are
    // multiplied by sP's zeroed pad cols 400..415 -> exact; max read 25616).
    f32x4 o0 = {0.f, 0.f, 0.f, 0.f}, o1 = {0.f, 0.f, 0.f, 0.f};
#pragma unroll
    for (int ks = 0; ks < 13; ks++) {
      const v8s pa =
          *reinterpret_cast<const v8s*>(&sP[wq * 16 + lr][ks * 32 + lg * 8]);
      const v8s bv0 = *reinterpret_cast<const v8s*>(v0p + ks * 32 + lg * 8);
      const v8s bv1 = *reinterpret_cast<const v8s*>(v1p + ks * 32 + lg * 8);
      __builtin_amdgcn_s_setprio(1);
      o0 = mfma16(pa, bv0, o0);
      o1 = mfma16(pa, bv1, o1);
      __builtin_amdgcn_s_setprio(0);
    }

#pragma unroll
    for (int r = 0; r < 4; r++) {
      const int row = rowb + r;
      if (row < 400) {
        ctx[cb + (long)row * 512 + lr] = f2bf(o0[r] * inv[r]);
        ctx[cb + (long)row * 512 + 16 + lr] = f2bf(o1[r] * inv[r]);
      }
    }
  }
}

// ---------------------------------------------------------------------------

extern "C" void kernel_launch(void* const* d_in, const int* in_sizes, int n_in,
                              void* d_out, int out_size, void* d_ws, size_t ws_size,
                              hipStream_t stream) {
  (void)in_sizes; (void)n_in; (void)out_size;

  const float* query = (const float*)d_in[0];
  const float* key   = (const float*)d_in[1];
  const float* value = (const float*)d_in[2];
  const float* Wq = (const float*)d_in[3];
  const float* bq = (const float*)d_in[4];
  const float* Wk = (const float*)d_in[5];
  const float* bk = (const float*)d_in[6];
  const float* Wv = (const float*)d_in[7];
  const float* bv = (const float*)d_in[8];
  const float* Wo = (const float*)d_in[9];
  const float* bo = (const float*)d_in[10];

  float* out = (float*)d_out;       // 39,321,600 f32
  float* sc  = out + 39321600ULL;   // 245,760,000 f32 (scores)
  float* vhb = sc + 245760000ULL;   // 39,321,600 f32

  char* ws = (char*)d_ws;
  unsigned short* wq_  = (unsigned short*)ws;                   // 78.6 MB
  unsigned short* wk_  = (unsigned short*)(ws + 78643200ULL);   // 78.6 MB
  unsigned short* wvt  = (unsigned short*)(ws + 157286400ULL);  // 78.6 MB
  unsigned short* wW   = (unsigned short*)(ws + 235929600ULL);  // 2 MB
  // ctx: dedicated region when workspace permits (no alias, no race surface).
  unsigned short* wctx = (ws_size >= 316669952ULL)
                             ? (unsigned short*)(ws + 238026752ULL)
                             : wq_;

  dim3 blk(256);

  hipLaunchKernelGGL(cvtw_k, dim3(128, 4), blk, 0, stream, Wq, Wk, Wv, Wo, wW);

  hipLaunchKernelGGL(proj_k, dim3(7200), blk, 0, stream, query, key, value, wW,
                     bq, bk, bv, wq_, wk_, vhb, wvt);

  hipLaunchKernelGGL(attn_k, dim3(1536), dim3(512), 0, stream, wq_, wk_, wvt,
                     sc, wctx);

  hipLaunchKernelGGL(outgemm_k, dim3(2400), blk, 0, stream, wctx, wW + 786432,
                     bo, out);
}